// Round 13
// baseline (204.481 us; speedup 1.0000x reference)
//
#include <hip/hip_runtime.h>
#include <math.h>

// Problem constants
#define DIM   384
#define NQKV  1152
#define IMG   56
#define ROWS_PER_B (IMG*IMG)           // 3136 pixels per batch image

typedef unsigned short u16;
typedef unsigned int u32;
typedef __attribute__((ext_vector_type(4))) float f32x4;
typedef __attribute__((ext_vector_type(8))) short s16x8;

__device__ __forceinline__ u16 f2b(float f) {           // fp32 -> bf16 RNE
    unsigned u = __float_as_uint(f);
    return (u16)((u + 0x7fffu + ((u >> 16) & 1u)) >> 16);
}

// async global->LDS, 16B/lane, dest = wave-uniform base + lane*16
__device__ __forceinline__ void gl2lds16(const void* g, void* l) {
    __builtin_amdgcn_global_load_lds(
        (const __attribute__((address_space(1))) void*)g,
        (__attribute__((address_space(3))) void*)l, 16, 0, 0);
}

__device__ __forceinline__ s16x8 pack8(float4 a, float4 b) {
    s16x8 w;
    w[0] = (short)f2b(a.x); w[1] = (short)f2b(a.y);
    w[2] = (short)f2b(a.z); w[3] = (short)f2b(a.w);
    w[4] = (short)f2b(b.x); w[5] = (short)f2b(b.y);
    w[6] = (short)f2b(b.z); w[7] = (short)f2b(b.w);
    return w;
}

// ---------------------------------------------------------------------------
// Kernel 1: masked relative-embedding table, 4 variants [4][64][64].
// Sinusoid math bit-faithful to numpy arange fill (verified R3). DO NOT TOUCH.
// ---------------------------------------------------------------------------
__global__ __launch_bounds__(256) void emb4_init_kernel(float* __restrict__ emb4) {
    int idx = blockIdx.x * 256 + threadIdx.x;
    if (idx >= 64 * 64) return;
    int q = idx >> 6, k = idx & 63;

    bool pad = (q >= 49) || (k >= 49);
    float base = 0.f;
    if (!pad) {
        const double step  = 1.0 / 7.0;
        const double delta = __dsub_rn(__dadd_rn(1.0, step), 1.0);
        double xk = __dadd_rn(1.0, __dmul_rn((double)k, delta));
        double xq = __dadd_rn(1.0, __dmul_rn((double)q, delta));
        int xi = (int)__dsub_rn(xk, xq);
        int yi = (k % 7) - (q % 7);
        int r = xi % 13; if (r < 0) r += 13;
        int c = yi % 13; if (c < 0) c += 13;
        const float scl = (float)(-0.7084877209212449);  // -log(10000)/13
        if ((c & 1) == 0) base = sinf((float)r * expf((float)c * scl));
        else              base = cosf((float)r * expf((float)(c - 1) * scl));
    }
    bool rmask = !pad && ((q >= 28) != (k >= 28));
    bool cmask = !pad && ((q % 7 >= 4) != (k % 7 >= 4));
    #pragma unroll
    for (int v = 0; v < 4; ++v) {
        float val = base;
        if (pad || ((v & 1) && rmask) || ((v & 2) && cmask)) val = -INFINITY;
        emb4[v * 4096 + idx] = val;
    }
}

// ---------------------------------------------------------------------------
// Weight conversion kernels (activation cvt now fused into the QKV GEMM)
// ---------------------------------------------------------------------------
__global__ __launch_bounds__(256) void cvt_transpose_bf16(
    const float* __restrict__ w, u16* __restrict__ wt, int R, int C) {
    int i = blockIdx.x * 256 + threadIdx.x;
    if (i >= R * C) return;
    int r = i / C, c = i % C;
    wt[(size_t)c * R + r] = f2b(w[i]);
}

// QKV transpose with de-interleaving row permutation: GEMM col n' = comp*384+ch
__global__ __launch_bounds__(256) void cvt_transpose_qkv(
    const float* __restrict__ w, u16* __restrict__ wt) {
    int i = blockIdx.x * 256 + threadIdx.x;
    if (i >= 384 * 1152) return;
    int k = i / 1152, col = i % 1152;
    int ch = col / 3, comp = col % 3;
    int np = comp * 384 + ch;
    wt[(size_t)np * 384 + k] = f2b(w[i]);
}

__global__ __launch_bounds__(256) void bias_perm_kernel(
    const float* __restrict__ b, float* __restrict__ bp) {
    int n = blockIdx.x * 256 + threadIdx.x;
    if (n >= 1152) return;
    int comp = n / 384, ch = n % 384;
    bp[n] = b[ch * 3 + comp];
}

// ---------------------------------------------------------------------------
// QKV MFMA GEMM, fp32 A staged DIRECTLY via global_load_lds (cvt pass fused).
// C[M][1152] = bf16(A_f32[M][384]) @ Bt[1152][384]^T + bias, bf16 out.
// A: LDS [128][32] fp32 (16KB/buf), rows = 128B = 8 x 16B slots; both-sides
//    swizzle phys slot8 = logical ^ (row&7); inverse folded into the per-lane
//    GLOBAL source (srcSlot = (lane&7)^(lane>>3)). 16 lanes -> 8 slots = 2-way
//    (free, m136). Fragment read = 2x ds_read_b128 + 8x f2b (bit-identical RNE
//    to the old cvt kernel). B: bf16, verified R8 swizzle (0 conflicts).
// dbuf, counted vmcnt: 6 issues/wave/tile (A:4 + B:2); after issuing t+1 ->
// 12 outstanding, vmcnt(6) waits exactly tile t (R9-verified skeleton).
// Grid: bijective XCD remap (m204, R8-verified).
// ---------------------------------------------------------------------------
__global__ __launch_bounds__(256) void mfma_gemm_qkv_f32(
    const float* __restrict__ A, const u16* __restrict__ Bt,
    const float* __restrict__ bias, u16* __restrict__ outb,
    int N, int K)
{
    __shared__ __align__(16) float Af[2][4096];   // [128][32] fp32, swizzled
    __shared__ __align__(16) u16   Bs[2][4096];   // [128][32] bf16, swizzled

    const int tid  = threadIdx.x;
    const int lane = tid & 63;
    const int wid  = tid >> 6;
    const int wr   = wid >> 1, wc = wid & 1;
    const int l15  = lane & 15, l4 = lane >> 4;

    // bijective XCD remap (m204)
    const int gx  = gridDim.x;
    const int nwg = gx * gridDim.y;
    int wg  = blockIdx.y * gx + blockIdx.x;
    int q8  = nwg >> 3, r8 = nwg & 7;
    int xcd = wg & 7, idx = wg >> 3;
    int nid = (xcd < r8 ? xcd * (q8 + 1) : r8 * (q8 + 1) + (xcd - r8) * q8) + idx;
    const int bm = nid / gx, bn = nid % gx;

    // A staging: wave wid covers rows wid*32..+31 in 4 issues of 8 rows.
    // lane -> row (lane>>3), phys slot (lane&7); source logical slot XOR row.
    const int arow  = lane >> 3;                       // 0..7 within issue
    const int aslot = (lane & 7) ^ arow;               // pre-swizzled src slot
    const float* pA[4];
    #pragma unroll
    for (int i = 0; i < 4; ++i)
        pA[i] = A + (size_t)(bm * 128 + wid * 32 + i * 8 + arow) * K + aslot * 4;

    // B staging (verified R8 geometry)
    const int bsrow = lane >> 2;
    const int bslot = (lane & 3) ^ ((bsrow >> 1) & 3);
    const u16* pB0 = Bt + (size_t)(bn * 128 +      wid * 16 + bsrow) * K + bslot * 8;
    const u16* pB1 = Bt + (size_t)(bn * 128 + 64 + wid * 16 + bsrow) * K + bslot * 8;

    f32x4 acc[4][4] = {};
    const int NT = K >> 5;

    #define STAGE(t, b)                                                       \
        do {                                                                  \
            const int _kt = (t) << 5;                                         \
            _Pragma("unroll")                                                 \
            for (int _i = 0; _i < 4; ++_i)                                    \
                gl2lds16(pA[_i] + _kt, &Af[b][(wid * 32 + _i * 8) * 32]);     \
            gl2lds16(pB0 + _kt, (u16*)((char*)Bs[b] + wid * 1024));           \
            gl2lds16(pB1 + _kt, (u16*)((char*)Bs[b] + 4096 + wid * 1024));    \
        } while (0)

    STAGE(0, 0);

    for (int t = 0; t < NT; ++t) {
        const int buf = t & 1;
        if (t + 1 < NT) {
            STAGE(t + 1, buf ^ 1);
            asm volatile("s_waitcnt vmcnt(6)" ::: "memory");   // tile t landed
        } else {
            asm volatile("s_waitcnt vmcnt(0)" ::: "memory");
        }
        __builtin_amdgcn_s_barrier();
        __builtin_amdgcn_sched_barrier(0);

        s16x8 af[4], bf[4];
        #pragma unroll
        for (int m = 0; m < 4; ++m) {
            int rm = wr * 64 + m * 16 + l15;
            int x7 = rm & 7;
            const float* rb = &Af[buf][rm * 32];
            float4 lo = *(const float4*)(rb + (((2 * l4)     ^ x7) << 2));
            float4 hi = *(const float4*)(rb + (((2 * l4 + 1) ^ x7) << 2));
            af[m] = pack8(lo, hi);
        }
        #pragma unroll
        for (int n = 0; n < 4; ++n) {
            int rn = wc * 64 + n * 16 + l15;
            bf[n] = *(const s16x8*)((const char*)Bs[buf] + rn * 64
                                    + ((l4 ^ ((rn >> 1) & 3)) << 4));
        }
        #pragma unroll
        for (int m = 0; m < 4; ++m)
            #pragma unroll
            for (int n = 0; n < 4; ++n)
                acc[m][n] = __builtin_amdgcn_mfma_f32_16x16x32_bf16(
                    af[m], bf[n], acc[m][n], 0, 0, 0);

        asm volatile("s_waitcnt lgkmcnt(0)" ::: "memory");   // reads done
        __builtin_amdgcn_sched_barrier(0);
        __builtin_amdgcn_s_barrier();                        // buf reusable
    }
    #undef STAGE

    const int grow0 = bm * 128 + wr * 64;
    const int gcol0 = bn * 128 + wc * 64;
    #pragma unroll
    for (int m = 0; m < 4; ++m) {
        #pragma unroll
        for (int n = 0; n < 4; ++n) {
            int col = gcol0 + n * 16 + l15;
            float bz = bias[col];
            #pragma unroll
            for (int r = 0; r < 4; ++r) {
                int row = grow0 + m * 16 + l4 * 4 + r;
                outb[(size_t)row * N + col] = f2b(acc[m][n][r] + bz);
            }
        }
    }
}

// ---------------------------------------------------------------------------
// Out-proj MFMA GEMM (R12-verified single-barrier ring, MODE 1 path).
// ---------------------------------------------------------------------------
__global__ __launch_bounds__(256) void mfma_gemm_out(
    const u16* __restrict__ A, const u16* __restrict__ Bt,
    const float* __restrict__ bias, float* __restrict__ outf,
    int N, int K)
{
    __shared__ __align__(16) u16 As[3][4096];
    __shared__ __align__(16) u16 Bs[3][4096];

    const int tid  = threadIdx.x;
    const int lane = tid & 63;
    const int wid  = tid >> 6;
    const int wr   = wid >> 1, wc = wid & 1;
    const int l15  = lane & 15, l4 = lane >> 4;

    const int gx  = gridDim.x;
    const int nwg = gx * gridDim.y;
    int wg  = blockIdx.y * gx + blockIdx.x;
    int q8  = nwg >> 3, r8 = nwg & 7;
    int xcd = wg & 7, idx = wg >> 3;
    int nid = (xcd < r8 ? xcd * (q8 + 1) : r8 * (q8 + 1) + (xcd - r8) * q8) + idx;
    const int bm = nid / gx, bn = nid % gx;

    const int srow  = lane >> 2;
    const int sslot = (lane & 3) ^ ((srow >> 1) & 3);

    const u16* pA0 = A  + (size_t)(bm * 128 +      wid * 16 + srow) * K + sslot * 8;
    const u16* pA1 = A  + (size_t)(bm * 128 + 64 + wid * 16 + srow) * K + sslot * 8;
    const u16* pB0 = Bt + (size_t)(bn * 128 +      wid * 16 + srow) * K + sslot * 8;
    const u16* pB1 = Bt + (size_t)(bn * 128 + 64 + wid * 16 + srow) * K + sslot * 8;

    f32x4 acc[4][4] = {};
    const int NT = K >> 5;

    #define STAGE(t)                                                          \
        do {                                                                  \
            const int _kt = (t) << 5;                                         \
            const int _rb = (t) % 3;                                          \
            gl2lds16(pA0 + _kt, (u16*)((char*)As[_rb] + wid * 1024));         \
            gl2lds16(pA1 + _kt, (u16*)((char*)As[_rb] + 4096 + wid * 1024));  \
            gl2lds16(pB0 + _kt, (u16*)((char*)Bs[_rb] + wid * 1024));         \
            gl2lds16(pB1 + _kt, (u16*)((char*)Bs[_rb] + 4096 + wid * 1024));  \
        } while (0)

    STAGE(0);
    STAGE(1);

    for (int t = 0; t < NT; ++t) {
        if (t + 1 < NT) {
            asm volatile("s_waitcnt vmcnt(4)" ::: "memory");
        } else {
            asm volatile("s_waitcnt vmcnt(0)" ::: "memory");
        }
        __builtin_amdgcn_s_barrier();
        if (t + 2 < NT) STAGE(t + 2);
        __builtin_amdgcn_sched_barrier(0);

        const int buf = t % 3;
        s16x8 af[4], bf[4];
        #pragma unroll
        for (int m = 0; m < 4; ++m) {
            int rm = wr * 64 + m * 16 + l15;
            af[m] = *(const s16x8*)((const char*)As[buf] + rm * 64
                                    + ((l4 ^ ((rm >> 1) & 3)) << 4));
        }
        #pragma unroll
        for (int n = 0; n < 4; ++n) {
            int rn = wc * 64 + n * 16 + l15;
            bf[n] = *(const s16x8*)((const char*)Bs[buf] + rn * 64
                                    + ((l4 ^ ((rn >> 1) & 3)) << 4));
        }
        #pragma unroll
        for (int m = 0; m < 4; ++m)
            #pragma unroll
            for (int n = 0; n < 4; ++n)
                acc[m][n] = __builtin_amdgcn_mfma_f32_16x16x32_bf16(
                    af[m], bf[n], acc[m][n], 0, 0, 0);
    }
    #undef STAGE

    const int grow0 = bm * 128 + wr * 64;
    const int gcol0 = bn * 128 + wc * 64;
    #pragma unroll
    for (int m = 0; m < 4; ++m) {
        #pragma unroll
        for (int n = 0; n < 4; ++n) {
            int col = gcol0 + n * 16 + l15;
            float bz = bias[col];
            #pragma unroll
            for (int r = 0; r < 4; ++r) {
                int row = grow0 + m * 16 + l4 * 4 + r;
                outf[(size_t)row * N + col] = acc[m][n][r] + bz;
            }
        }
    }
}

// ---------------------------------------------------------------------------
// Kernel 3: MFMA windowed attention, stageless (verified R7).
// NEW: T5 s_setprio(1) around both MFMA clusters (independent unsynced
// waves = exactly m191's +4-7% regime).
// ---------------------------------------------------------------------------
__global__ __launch_bounds__(256) void attn_mfma_kernel(
    const u16* __restrict__ qkv, const float* __restrict__ emb4,
    u16* __restrict__ att)
{
    __shared__ __align__(16) u16 P4[4][64 * 72];   // 36864 B
    __shared__ int rowIn[64];
    __shared__ int rowOut[64];

    const int tid  = threadIdx.x;
    const int lane = tid & 63;
    const int wid  = tid >> 6;
    const int l15  = lane & 15, l4 = lane >> 4;

    const int blk = blockIdx.x;
    const int hg  = blk % 3;
    const int win = (blk / 3) & 63;
    const int b   = blk / 192;
    const int bw  = win & 7, bh = win >> 3;
    const int head = hg * 4 + wid;

    if (tid < 64) {                                 // roll(-4,-4) gather LUT
        int pix = tid;
        int gr = (bh * 7 + pix / 7 + 4) % IMG;
        int gc = (bw * 7 + pix % 7 + 4) % IMG;
        rowIn[pix] = (b * IMG + gr) * IMG + gc;
    } else if (tid < 128) {                         // roll(+3,+3) scatter LUT
        int q = tid - 64;
        int fr = (bh * 7 + q / 7 + 3) % IMG;
        int fc = (bw * 7 + q % 7 + 3) % IMG;
        rowOut[q] = (b * IMG + fr) * IMG + fc;
    }
    __syncthreads();

    s16x8 qf[4], kf[4];
    #pragma unroll
    for (int n = 0; n < 4; ++n) {
        int pix = n * 16 + l15;
        size_t base = (size_t)rowIn[pix] * NQKV + head * 32 + l4 * 8;
        qf[n] = *(const s16x8*)(qkv + base);          // Q
        kf[n] = *(const s16x8*)(qkv + base + 384);    // K
    }

    f32x4 sc[4][4] = {};
    __builtin_amdgcn_s_setprio(1);
    #pragma unroll
    for (int m = 0; m < 4; ++m)
        #pragma unroll
        for (int n = 0; n < 4; ++n)
            sc[m][n] = __builtin_amdgcn_mfma_f32_16x16x32_bf16(
                kf[m], qf[n], sc[m][n], 0, 0, 0);
    __builtin_amdgcn_s_setprio(0);

    const float scale = 0.17677669529663687f;        // 1/sqrt(32)
    const float* ev = emb4 + ((bh == 7 ? 1 : 0) + (bw == 7 ? 2 : 0)) * 4096;
    u16* P = P4[wid];
    u32* P32 = (u32*)P;

    #pragma unroll
    for (int n = 0; n < 4; ++n) {
        const int q = n * 16 + l15;
        float vals[4][4];
        float mx = -INFINITY;
        #pragma unroll
        for (int m = 0; m < 4; ++m) {
            float4 e4 = *(const float4*)(ev + q * 64 + m * 16 + l4 * 4);
            #pragma unroll
            for (int r = 0; r < 4; ++r) {
                float v = sc[m][n][r] * scale + ((const float*)&e4)[r];
                vals[m][r] = v;
                mx = fmaxf(mx, v);
            }
        }
        mx = fmaxf(mx, __shfl_xor(mx, 16));
        mx = fmaxf(mx, __shfl_xor(mx, 32));
        float sum = 0.f;
        #pragma unroll
        for (int m = 0; m < 4; ++m)
            #pragma unroll
            for (int r = 0; r < 4; ++r) {
                float p = __expf(vals[m][r] - mx);
                vals[m][r] = p;
                sum += p;
            }
        sum += __shfl_xor(sum, 16);
        sum += __shfl_xor(sum, 32);
        float inv = 1.f / sum;
        #pragma unroll
        for (int m = 0; m < 4; ++m) {
            u32 w0 = (u32)f2b(vals[m][0] * inv) | ((u32)f2b(vals[m][1] * inv) << 16);
            u32 w1 = (u32)f2b(vals[m][2] * inv) | ((u32)f2b(vals[m][3] * inv) << 16);
            int bidx = q * 36 + m * 8 + l4 * 2;
            P32[bidx]     = w0;
            P32[bidx + 1] = w1;
        }
    }
    // per-wave private LDS RAW: compiler inserts lgkmcnt waits; no barrier.

    f32x4 o[4][2] = {};
    #pragma unroll
    for (int kh = 0; kh < 2; ++kh) {
        s16x8 pf[4];
        #pragma unroll
        for (int mq = 0; mq < 4; ++mq)
            pf[mq] = *(const s16x8*)&P[(mq * 16 + l15) * 72 + kh * 32 + l4 * 8];
        s16x8 vf[2];
        #pragma unroll
        for (int ne = 0; ne < 2; ++ne) {
            #pragma unroll
            for (int j = 0; j < 8; ++j) {
                int pix = kh * 32 + l4 * 8 + j;
                vf[ne][j] = (short)qkv[(size_t)rowIn[pix] * NQKV + 768
                                       + head * 32 + ne * 16 + l15];
            }
        }
        __builtin_amdgcn_s_setprio(1);
        #pragma unroll
        for (int mq = 0; mq < 4; ++mq)
            #pragma unroll
            for (int ne = 0; ne < 2; ++ne)
                o[mq][ne] = __builtin_amdgcn_mfma_f32_16x16x32_bf16(
                    pf[mq], vf[ne], o[mq][ne], 0, 0, 0);
        __builtin_amdgcn_s_setprio(0);
    }

    #pragma unroll
    for (int mq = 0; mq < 4; ++mq) {
        #pragma unroll
        for (int r = 0; r < 4; ++r) {
            int q = mq * 16 + l4 * 4 + r;
            if (q < 49) {
                size_t rowb = (size_t)rowOut[q] * DIM + head * 32;
                #pragma unroll
                for (int ne = 0; ne < 2; ++ne)
                    att[rowb + ne * 16 + l15] = f2b(o[mq][ne][r]);
            }
        }
    }
}

// ---------------------------------------------------------------------------
extern "C" void kernel_launch(void* const* d_in, const int* in_sizes, int n_in,
                              void* d_out, int out_size, void* d_ws, size_t ws_size,
                              hipStream_t stream) {
    const float* x     = (const float*)d_in[0];
    const float* w_qkv = (const float*)d_in[1];
    const float* b_qkv = (const float*)d_in[2];
    const float* w_out = (const float*)d_in[3];
    const float* b_out = (const float*)d_in[4];
    float* out = (float*)d_out;

    char* wsp = (char*)d_ws;
    float* emb4  = (float*)wsp;                                  // 64 KB
    u16*   wqkvt = (u16*)(wsp + 65536);                          // [1152][384]
    u16*   woutt = (u16*)(wsp + 65536 + 884736);                 // [384][384]
    float* bqkvp = (float*)(wsp + 65536 + 884736 + 294912);      // [1152]
    const size_t fixed = 65536 + 884736 + 294912 + 4608;         // 1,249,792 B

    // per-batch chunk bytes: qkv (bf16) + att (bf16); x read in place
    const size_t perb = (size_t)ROWS_PER_B * (NQKV + DIM) * 2;   // 9,633,792
    int nb = 16;
    while (nb > 2 && fixed + (size_t)nb * perb > ws_size) nb >>= 1;

    u16* qkvb = (u16*)(wsp + fixed);
    u16* attb = qkvb + (size_t)nb * ROWS_PER_B * NQKV;

    emb4_init_kernel<<<16, 256, 0, stream>>>(emb4);
    cvt_transpose_qkv<<<(384 * 1152 + 255) / 256, 256, 0, stream>>>(w_qkv, wqkvt);
    cvt_transpose_bf16<<<(384 * 384 + 255) / 256, 256, 0, stream>>>(w_out, woutt, 384, 384);
    bias_perm_kernel<<<5, 256, 0, stream>>>(b_qkv, bqkvp);

    for (int b0 = 0; b0 < 16; b0 += nb) {
        const int rows = nb * ROWS_PER_B;
        const float* xa = x + (size_t)b0 * ROWS_PER_B * DIM;

        mfma_gemm_qkv_f32<<<dim3(NQKV / 128, rows / 128), 256, 0, stream>>>(
            xa, wqkvt, bqkvp, qkvb, NQKV, DIM);

        attn_mfma_kernel<<<nb * 192, 256, 0, stream>>>(qkvb, emb4, attb);

        mfma_gemm_out<<<dim3(DIM / 128, rows / 128), 256, 0, stream>>>(
            attb, woutt, b_out, out + (size_t)b0 * ROWS_PER_B * DIM, DIM, DIM);
    }
}

// Round 14
// 180.923 us; speedup vs baseline: 1.1302x; 1.1302x over previous
//
#include <hip/hip_runtime.h>
#include <math.h>

// Problem constants
#define DIM   384
#define NQKV  1152
#define IMG   56
#define ROWS_PER_B (IMG*IMG)           // 3136 pixels per batch image

typedef unsigned short u16;
typedef unsigned int u32;
typedef __attribute__((ext_vector_type(4))) float f32x4;
typedef __attribute__((ext_vector_type(8))) short s16x8;

__device__ __forceinline__ u16 f2b(float f) {           // fp32 -> bf16 RNE
    unsigned u = __float_as_uint(f);
    return (u16)((u + 0x7fffu + ((u >> 16) & 1u)) >> 16);
}

// async global->LDS, 16B/lane, dest = wave-uniform base + lane*16
__device__ __forceinline__ void gl2lds16(const void* g, void* l) {
    __builtin_amdgcn_global_load_lds(
        (const __attribute__((address_space(1))) void*)g,
        (__attribute__((address_space(3))) void*)l, 16, 0, 0);
}

// ---------------------------------------------------------------------------
// Kernel 1: masked relative-embedding table, 4 variants [4][64][64].
// Sinusoid math bit-faithful to numpy arange fill (verified R3). DO NOT TOUCH.
// ---------------------------------------------------------------------------
__global__ __launch_bounds__(256) void emb4_init_kernel(float* __restrict__ emb4) {
    int idx = blockIdx.x * 256 + threadIdx.x;
    if (idx >= 64 * 64) return;
    int q = idx >> 6, k = idx & 63;

    bool pad = (q >= 49) || (k >= 49);
    float base = 0.f;
    if (!pad) {
        const double step  = 1.0 / 7.0;
        const double delta = __dsub_rn(__dadd_rn(1.0, step), 1.0);
        double xk = __dadd_rn(1.0, __dmul_rn((double)k, delta));
        double xq = __dadd_rn(1.0, __dmul_rn((double)q, delta));
        int xi = (int)__dsub_rn(xk, xq);
        int yi = (k % 7) - (q % 7);
        int r = xi % 13; if (r < 0) r += 13;
        int c = yi % 13; if (c < 0) c += 13;
        const float scl = (float)(-0.7084877209212449);  // -log(10000)/13
        if ((c & 1) == 0) base = sinf((float)r * expf((float)c * scl));
        else              base = cosf((float)r * expf((float)(c - 1) * scl));
    }
    bool rmask = !pad && ((q >= 28) != (k >= 28));
    bool cmask = !pad && ((q % 7 >= 4) != (k % 7 >= 4));
    #pragma unroll
    for (int v = 0; v < 4; ++v) {
        float val = base;
        if (pad || ((v & 1) && rmask) || ((v & 2) && cmask)) val = -INFINITY;
        emb4[v * 4096 + idx] = val;
    }
}

// ---------------------------------------------------------------------------
// Conversion kernels
// ---------------------------------------------------------------------------
__global__ __launch_bounds__(256) void cvt_f32_bf16(
    const float* __restrict__ in, u16* __restrict__ out, int n4) {
    int i = blockIdx.x * 256 + threadIdx.x;
    if (i >= n4) return;
    float4 v = ((const float4*)in)[i];
    ushort4 o;
    o.x = f2b(v.x); o.y = f2b(v.y); o.z = f2b(v.z); o.w = f2b(v.w);
    ((ushort4*)out)[i] = o;
}

__global__ __launch_bounds__(256) void cvt_transpose_bf16(
    const float* __restrict__ w, u16* __restrict__ wt, int R, int C) {
    int i = blockIdx.x * 256 + threadIdx.x;
    if (i >= R * C) return;
    int r = i / C, c = i % C;
    wt[(size_t)c * R + r] = f2b(w[i]);
}

// QKV transpose with de-interleaving row permutation: GEMM col n' = comp*384+ch
__global__ __launch_bounds__(256) void cvt_transpose_qkv(
    const float* __restrict__ w, u16* __restrict__ wt) {
    int i = blockIdx.x * 256 + threadIdx.x;
    if (i >= 384 * 1152) return;
    int k = i / 1152, col = i % 1152;
    int ch = col / 3, comp = col % 3;
    int np = comp * 384 + ch;
    wt[(size_t)np * 384 + k] = f2b(w[i]);
}

__global__ __launch_bounds__(256) void bias_perm_kernel(
    const float* __restrict__ b, float* __restrict__ bp) {
    int n = blockIdx.x * 256 + threadIdx.x;
    if (n >= 1152) return;
    int comp = n / 384, ch = n % 384;
    bp[n] = b[ch * 3 + comp];
}

// ---------------------------------------------------------------------------
// MFMA bf16 GEMM: C[M][N] = A[M][K] @ Bt[N][K]^T + bias.
// 128x128 tile, NEW BK=64 (6 K-steps instead of 12: halves every sync event;
// the BK=32 plateau at 86us was sync-bound — R9/R11/R12 all landed 86+-1).
// 4 waves (64x64 quadrants, 4x4 frags of 16x16x32, 2 k-subtiles per step).
// LDS [128][64] bf16 (16KB) x2 operands x2 dbuf = 64KB -> 2 blocks/CU.
// Swizzle (rule 21, both sides): rows = 8 x 16B slots; phys slot8 =
// logical ^ (row&7); inverse folded into gload source slot (lane&7)^(lane>>3).
// Fragment read slot = (kk*4+l4)^(row&7): 16 lanes -> 8 slots -> 2-way (free).
// Counted vmcnt dbuf: 8 issues/wave/tile; after staging t+1 -> 16 outstanding,
// vmcnt(8) waits exactly tile t (R9-verified skeleton).
// Grid: bijective XCD remap (m204, R8-verified: FETCH 167->32 MB).
// MODE 0: bf16 out (QKV). MODE 1: fp32 out (final projection).
// ---------------------------------------------------------------------------
template <int MODE>
__global__ __launch_bounds__(256) void mfma_gemm(
    const u16* __restrict__ A, const u16* __restrict__ Bt,
    const float* __restrict__ bias,
    u16* __restrict__ outb, float* __restrict__ outf,
    int N, int K)
{
    __shared__ __align__(16) u16 As[2][8192];   // [128][64] swizzled
    __shared__ __align__(16) u16 Bs[2][8192];

    const int tid  = threadIdx.x;
    const int lane = tid & 63;
    const int wid  = tid >> 6;
    const int wr   = wid >> 1, wc = wid & 1;
    const int l15  = lane & 15, l4 = lane >> 4;

    // bijective XCD remap (m204): contiguous chunk of blocks per XCD
    const int gx  = gridDim.x;
    const int nwg = gx * gridDim.y;
    int wg  = blockIdx.y * gx + blockIdx.x;
    int q8  = nwg >> 3, r8 = nwg & 7;
    int xcd = wg & 7, idx = wg >> 3;
    int nid = (xcd < r8 ? xcd * (q8 + 1) : r8 * (q8 + 1) + (xcd - r8) * q8) + idx;
    const int bm = nid / gx, bn = nid % gx;

    // staging: issue i covers rows wid*32 + i*8 + (lane>>3); phys slot lane&7.
    // source logical slot = (lane&7) ^ (lane>>3)  (row&7 == lane>>3).
    const int srow  = lane >> 3;                 // 0..7 within an issue
    const int sslot = (lane & 7) ^ srow;         // pre-swizzled source slot
    const u16* pA[4];
    const u16* pB[4];
    #pragma unroll
    for (int i = 0; i < 4; ++i) {
        pA[i] = A  + (size_t)(bm * 128 + wid * 32 + i * 8 + srow) * K + sslot * 8;
        pB[i] = Bt + (size_t)(bn * 128 + wid * 32 + i * 8 + srow) * K + sslot * 8;
    }

    f32x4 acc[4][4] = {};
    const int NT = K >> 6;                        // BK = 64

    #define STAGE(t, b)                                                       \
        do {                                                                  \
            const int _kt = (t) << 6;                                         \
            _Pragma("unroll")                                                 \
            for (int _i = 0; _i < 4; ++_i) {                                  \
                gl2lds16(pA[_i] + _kt, &As[b][(wid * 32 + _i * 8) * 64]);     \
                gl2lds16(pB[_i] + _kt, &Bs[b][(wid * 32 + _i * 8) * 64]);     \
            }                                                                 \
        } while (0)

    STAGE(0, 0);

    for (int t = 0; t < NT; ++t) {
        const int buf = t & 1;
        if (t + 1 < NT) {
            STAGE(t + 1, buf ^ 1);
            asm volatile("s_waitcnt vmcnt(8)" ::: "memory");   // tile t landed
        } else {
            asm volatile("s_waitcnt vmcnt(0)" ::: "memory");
        }
        __builtin_amdgcn_s_barrier();          // tile t visible to all waves
        __builtin_amdgcn_sched_barrier(0);

        #pragma unroll
        for (int kk = 0; kk < 2; ++kk) {
            s16x8 af[4], bf[4];
            #pragma unroll
            for (int m = 0; m < 4; ++m) {
                int rm = wr * 64 + m * 16 + l15;
                int sl = (kk * 4 + l4) ^ (rm & 7);
                af[m] = *(const s16x8*)&As[buf][rm * 64 + sl * 8];
            }
            #pragma unroll
            for (int n = 0; n < 4; ++n) {
                int rn = wc * 64 + n * 16 + l15;
                int sl = (kk * 4 + l4) ^ (rn & 7);
                bf[n] = *(const s16x8*)&Bs[buf][rn * 64 + sl * 8];
            }
            #pragma unroll
            for (int m = 0; m < 4; ++m)
                #pragma unroll
                for (int n = 0; n < 4; ++n)
                    acc[m][n] = __builtin_amdgcn_mfma_f32_16x16x32_bf16(
                        af[m], bf[n], acc[m][n], 0, 0, 0);
        }

        // reads of buf complete before iter t+1 re-stages it
        asm volatile("s_waitcnt lgkmcnt(0)" ::: "memory");
        __builtin_amdgcn_sched_barrier(0);
        __builtin_amdgcn_s_barrier();
    }
    #undef STAGE

    const int grow0 = bm * 128 + wr * 64;
    const int gcol0 = bn * 128 + wc * 64;
    #pragma unroll
    for (int m = 0; m < 4; ++m) {
        #pragma unroll
        for (int n = 0; n < 4; ++n) {
            int col = gcol0 + n * 16 + l15;
            float bz = bias[col];
            #pragma unroll
            for (int r = 0; r < 4; ++r) {
                int row = grow0 + m * 16 + l4 * 4 + r;
                float v = acc[m][n][r] + bz;
                if constexpr (MODE == 0)
                    outb[(size_t)row * N + col] = f2b(v);
                else
                    outf[(size_t)row * N + col] = v;
            }
        }
    }
}

// ---------------------------------------------------------------------------
// Kernel 3: MFMA windowed attention, stageless (verified R7) + T5 setprio.
// ---------------------------------------------------------------------------
__global__ __launch_bounds__(256) void attn_mfma_kernel(
    const u16* __restrict__ qkv, const float* __restrict__ emb4,
    u16* __restrict__ att)
{
    __shared__ __align__(16) u16 P4[4][64 * 72];   // 36864 B
    __shared__ int rowIn[64];
    __shared__ int rowOut[64];

    const int tid  = threadIdx.x;
    const int lane = tid & 63;
    const int wid  = tid >> 6;
    const int l15  = lane & 15, l4 = lane >> 4;

    const int blk = blockIdx.x;
    const int hg  = blk % 3;
    const int win = (blk / 3) & 63;
    const int b   = blk / 192;
    const int bw  = win & 7, bh = win >> 3;
    const int head = hg * 4 + wid;

    if (tid < 64) {                                 // roll(-4,-4) gather LUT
        int pix = tid;
        int gr = (bh * 7 + pix / 7 + 4) % IMG;
        int gc = (bw * 7 + pix % 7 + 4) % IMG;
        rowIn[pix] = (b * IMG + gr) * IMG + gc;
    } else if (tid < 128) {                         // roll(+3,+3) scatter LUT
        int q = tid - 64;
        int fr = (bh * 7 + q / 7 + 3) % IMG;
        int fc = (bw * 7 + q % 7 + 3) % IMG;
        rowOut[q] = (b * IMG + fr) * IMG + fc;
    }
    __syncthreads();

    s16x8 qf[4], kf[4];
    #pragma unroll
    for (int n = 0; n < 4; ++n) {
        int pix = n * 16 + l15;
        size_t base = (size_t)rowIn[pix] * NQKV + head * 32 + l4 * 8;
        qf[n] = *(const s16x8*)(qkv + base);          // Q
        kf[n] = *(const s16x8*)(qkv + base + 384);    // K
    }

    f32x4 sc[4][4] = {};
    __builtin_amdgcn_s_setprio(1);
    #pragma unroll
    for (int m = 0; m < 4; ++m)
        #pragma unroll
        for (int n = 0; n < 4; ++n)
            sc[m][n] = __builtin_amdgcn_mfma_f32_16x16x32_bf16(
                kf[m], qf[n], sc[m][n], 0, 0, 0);
    __builtin_amdgcn_s_setprio(0);

    const float scale = 0.17677669529663687f;        // 1/sqrt(32)
    const float* ev = emb4 + ((bh == 7 ? 1 : 0) + (bw == 7 ? 2 : 0)) * 4096;
    u16* P = P4[wid];
    u32* P32 = (u32*)P;

    #pragma unroll
    for (int n = 0; n < 4; ++n) {
        const int q = n * 16 + l15;
        float vals[4][4];
        float mx = -INFINITY;
        #pragma unroll
        for (int m = 0; m < 4; ++m) {
            float4 e4 = *(const float4*)(ev + q * 64 + m * 16 + l4 * 4);
            #pragma unroll
            for (int r = 0; r < 4; ++r) {
                float v = sc[m][n][r] * scale + ((const float*)&e4)[r];
                vals[m][r] = v;
                mx = fmaxf(mx, v);
            }
        }
        mx = fmaxf(mx, __shfl_xor(mx, 16));
        mx = fmaxf(mx, __shfl_xor(mx, 32));
        float sum = 0.f;
        #pragma unroll
        for (int m = 0; m < 4; ++m)
            #pragma unroll
            for (int r = 0; r < 4; ++r) {
                float p = __expf(vals[m][r] - mx);
                vals[m][r] = p;
                sum += p;
            }
        sum += __shfl_xor(sum, 16);
        sum += __shfl_xor(sum, 32);
        float inv = 1.f / sum;
        #pragma unroll
        for (int m = 0; m < 4; ++m) {
            u32 w0 = (u32)f2b(vals[m][0] * inv) | ((u32)f2b(vals[m][1] * inv) << 16);
            u32 w1 = (u32)f2b(vals[m][2] * inv) | ((u32)f2b(vals[m][3] * inv) << 16);
            int bidx = q * 36 + m * 8 + l4 * 2;
            P32[bidx]     = w0;
            P32[bidx + 1] = w1;
        }
    }
    // per-wave private LDS RAW: compiler inserts lgkmcnt waits; no barrier.

    f32x4 o[4][2] = {};
    #pragma unroll
    for (int kh = 0; kh < 2; ++kh) {
        s16x8 pf[4];
        #pragma unroll
        for (int mq = 0; mq < 4; ++mq)
            pf[mq] = *(const s16x8*)&P[(mq * 16 + l15) * 72 + kh * 32 + l4 * 8];
        s16x8 vf[2];
        #pragma unroll
        for (int ne = 0; ne < 2; ++ne) {
            #pragma unroll
            for (int j = 0; j < 8; ++j) {
                int pix = kh * 32 + l4 * 8 + j;
                vf[ne][j] = (short)qkv[(size_t)rowIn[pix] * NQKV + 768
                                       + head * 32 + ne * 16 + l15];
            }
        }
        __builtin_amdgcn_s_setprio(1);
        #pragma unroll
        for (int mq = 0; mq < 4; ++mq)
            #pragma unroll
            for (int ne = 0; ne < 2; ++ne)
                o[mq][ne] = __builtin_amdgcn_mfma_f32_16x16x32_bf16(
                    pf[mq], vf[ne], o[mq][ne], 0, 0, 0);
        __builtin_amdgcn_s_setprio(0);
    }

    #pragma unroll
    for (int mq = 0; mq < 4; ++mq) {
        #pragma unroll
        for (int r = 0; r < 4; ++r) {
            int q = mq * 16 + l4 * 4 + r;
            if (q < 49) {
                size_t rowb = (size_t)rowOut[q] * DIM + head * 32;
                #pragma unroll
                for (int ne = 0; ne < 2; ++ne)
                    att[rowb + ne * 16 + l15] = f2b(o[mq][ne][r]);
            }
        }
    }
}

// ---------------------------------------------------------------------------
extern "C" void kernel_launch(void* const* d_in, const int* in_sizes, int n_in,
                              void* d_out, int out_size, void* d_ws, size_t ws_size,
                              hipStream_t stream) {
    const float* x     = (const float*)d_in[0];
    const float* w_qkv = (const float*)d_in[1];
    const float* b_qkv = (const float*)d_in[2];
    const float* w_out = (const float*)d_in[3];
    const float* b_out = (const float*)d_in[4];
    float* out = (float*)d_out;

    char* wsp = (char*)d_ws;
    float* emb4  = (float*)wsp;                                  // 64 KB
    u16*   wqkvt = (u16*)(wsp + 65536);                          // [1152][384]
    u16*   woutt = (u16*)(wsp + 65536 + 884736);                 // [384][384]
    float* bqkvp = (float*)(wsp + 65536 + 884736 + 294912);      // [1152]
    const size_t fixed = 65536 + 884736 + 294912 + 4608;         // 1,249,792 B

    // per-batch chunk bytes: xb + qkv + att, all bf16
    const size_t perb = (size_t)ROWS_PER_B * (DIM + NQKV + DIM) * 2; // 12,042,240
    int nb = 16;
    while (nb > 2 && fixed + (size_t)nb * perb > ws_size) nb >>= 1;

    u16* xb   = (u16*)(wsp + fixed);
    u16* qkvb = xb   + (size_t)nb * ROWS_PER_B * DIM;
    u16* attb = qkvb + (size_t)nb * ROWS_PER_B * NQKV;

    emb4_init_kernel<<<16, 256, 0, stream>>>(emb4);
    cvt_transpose_qkv<<<(384 * 1152 + 255) / 256, 256, 0, stream>>>(w_qkv, wqkvt);
    cvt_transpose_bf16<<<(384 * 384 + 255) / 256, 256, 0, stream>>>(w_out, woutt, 384, 384);
    bias_perm_kernel<<<5, 256, 0, stream>>>(b_qkv, bqkvp);

    for (int b0 = 0; b0 < 16; b0 += nb) {
        const int rows = nb * ROWS_PER_B;
        const float* xa = x + (size_t)b0 * ROWS_PER_B * DIM;

        cvt_f32_bf16<<<(rows * DIM / 4 + 255) / 256, 256, 0, stream>>>(
            xa, xb, rows * DIM / 4);

        mfma_gemm<0><<<dim3(NQKV / 128, rows / 128), 256, 0, stream>>>(
            xb, wqkvt, bqkvp, qkvb, nullptr, NQKV, DIM);

        attn_mfma_kernel<<<nb * 192, 256, 0, stream>>>(qkvb, emb4, attb);

        mfma_gemm<1><<<dim3(DIM / 128, rows / 128), 256, 0, stream>>>(
            attb, woutt, b_out, nullptr, out + (size_t)b0 * ROWS_PER_B * DIM, DIM, DIM);
    }
}

// Round 15
// 178.374 us; speedup vs baseline: 1.1464x; 1.0143x over previous
//
#include <hip/hip_runtime.h>
#include <math.h>

// Problem constants
#define DIM   384
#define NQKV  1152
#define IMG   56
#define ROWS_PER_B (IMG*IMG)           // 3136 pixels per batch image

typedef unsigned short u16;
typedef unsigned int u32;
typedef __attribute__((ext_vector_type(4))) float f32x4;
typedef __attribute__((ext_vector_type(8))) short s16x8;

__device__ __forceinline__ u16 f2b(float f) {           // fp32 -> bf16 RNE
    unsigned u = __float_as_uint(f);
    return (u16)((u + 0x7fffu + ((u >> 16) & 1u)) >> 16);
}

// async global->LDS, 16B/lane, dest = wave-uniform base + lane*16
__device__ __forceinline__ void gl2lds16(const void* g, void* l) {
    __builtin_amdgcn_global_load_lds(
        (const __attribute__((address_space(1))) void*)g,
        (__attribute__((address_space(3))) void*)l, 16, 0, 0);
}

// ---------------------------------------------------------------------------
// Kernel 1: masked relative-embedding table, 4 variants [4][64][64].
// Sinusoid math bit-faithful to numpy arange fill (verified R3). DO NOT TOUCH.
// ---------------------------------------------------------------------------
__global__ __launch_bounds__(256) void emb4_init_kernel(float* __restrict__ emb4) {
    int idx = blockIdx.x * 256 + threadIdx.x;
    if (idx >= 64 * 64) return;
    int q = idx >> 6, k = idx & 63;

    bool pad = (q >= 49) || (k >= 49);
    float base = 0.f;
    if (!pad) {
        const double step  = 1.0 / 7.0;
        const double delta = __dsub_rn(__dadd_rn(1.0, step), 1.0);
        double xk = __dadd_rn(1.0, __dmul_rn((double)k, delta));
        double xq = __dadd_rn(1.0, __dmul_rn((double)q, delta));
        int xi = (int)__dsub_rn(xk, xq);
        int yi = (k % 7) - (q % 7);
        int r = xi % 13; if (r < 0) r += 13;
        int c = yi % 13; if (c < 0) c += 13;
        const float scl = (float)(-0.7084877209212449);  // -log(10000)/13
        if ((c & 1) == 0) base = sinf((float)r * expf((float)c * scl));
        else              base = cosf((float)r * expf((float)(c - 1) * scl));
    }
    bool rmask = !pad && ((q >= 28) != (k >= 28));
    bool cmask = !pad && ((q % 7 >= 4) != (k % 7 >= 4));
    #pragma unroll
    for (int v = 0; v < 4; ++v) {
        float val = base;
        if (pad || ((v & 1) && rmask) || ((v & 2) && cmask)) val = -INFINITY;
        emb4[v * 4096 + idx] = val;
    }
}

// ---------------------------------------------------------------------------
// Conversion kernels
// ---------------------------------------------------------------------------
__global__ __launch_bounds__(256) void cvt_f32_bf16(
    const float* __restrict__ in, u16* __restrict__ out, int n4) {
    int i = blockIdx.x * 256 + threadIdx.x;
    if (i >= n4) return;
    float4 v = ((const float4*)in)[i];
    ushort4 o;
    o.x = f2b(v.x); o.y = f2b(v.y); o.z = f2b(v.z); o.w = f2b(v.w);
    ((ushort4*)out)[i] = o;
}

__global__ __launch_bounds__(256) void cvt_transpose_bf16(
    const float* __restrict__ w, u16* __restrict__ wt, int R, int C) {
    int i = blockIdx.x * 256 + threadIdx.x;
    if (i >= R * C) return;
    int r = i / C, c = i % C;
    wt[(size_t)c * R + r] = f2b(w[i]);
}

// QKV transpose with de-interleaving row permutation: GEMM col n' = comp*384+ch
__global__ __launch_bounds__(256) void cvt_transpose_qkv(
    const float* __restrict__ w, u16* __restrict__ wt) {
    int i = blockIdx.x * 256 + threadIdx.x;
    if (i >= 384 * 1152) return;
    int k = i / 1152, col = i % 1152;
    int ch = col / 3, comp = col % 3;
    int np = comp * 384 + ch;
    wt[(size_t)np * 384 + k] = f2b(w[i]);
}

__global__ __launch_bounds__(256) void bias_perm_kernel(
    const float* __restrict__ b, float* __restrict__ bp) {
    int n = blockIdx.x * 256 + threadIdx.x;
    if (n >= 1152) return;
    int comp = n / 384, ch = n % 384;
    bp[n] = b[ch * 3 + comp];
}

// ---------------------------------------------------------------------------
// MFMA bf16 GEMM: C[M][N] = A[M][K] @ Bt[N][K]^T + bias.
// 128x128 tile, NEW BK=64 (6 K-steps instead of 12: halves every sync event;
// the BK=32 plateau at 86us was sync-bound — R9/R11/R12 all landed 86+-1).
// 4 waves (64x64 quadrants, 4x4 frags of 16x16x32, 2 k-subtiles per step).
// LDS [128][64] bf16 (16KB) x2 operands x2 dbuf = 64KB -> 2 blocks/CU.
// Swizzle (rule 21, both sides): rows = 8 x 16B slots; phys slot8 =
// logical ^ (row&7); inverse folded into gload source slot (lane&7)^(lane>>3).
// Fragment read slot = (kk*4+l4)^(row&7): 16 lanes -> 8 slots -> 2-way (free).
// Counted vmcnt dbuf: 8 issues/wave/tile; after staging t+1 -> 16 outstanding,
// vmcnt(8) waits exactly tile t (R9-verified skeleton).
// Grid: bijective XCD remap (m204, R8-verified: FETCH 167->32 MB).
// MODE 0: bf16 out (QKV). MODE 1: fp32 out (final projection).
// ---------------------------------------------------------------------------
template <int MODE>
__global__ __launch_bounds__(256) void mfma_gemm(
    const u16* __restrict__ A, const u16* __restrict__ Bt,
    const float* __restrict__ bias,
    u16* __restrict__ outb, float* __restrict__ outf,
    int N, int K)
{
    __shared__ __align__(16) u16 As[2][8192];   // [128][64] swizzled
    __shared__ __align__(16) u16 Bs[2][8192];

    const int tid  = threadIdx.x;
    const int lane = tid & 63;
    const int wid  = tid >> 6;
    const int wr   = wid >> 1, wc = wid & 1;
    const int l15  = lane & 15, l4 = lane >> 4;

    // bijective XCD remap (m204): contiguous chunk of blocks per XCD
    const int gx  = gridDim.x;
    const int nwg = gx * gridDim.y;
    int wg  = blockIdx.y * gx + blockIdx.x;
    int q8  = nwg >> 3, r8 = nwg & 7;
    int xcd = wg & 7, idx = wg >> 3;
    int nid = (xcd < r8 ? xcd * (q8 + 1) : r8 * (q8 + 1) + (xcd - r8) * q8) + idx;
    const int bm = nid / gx, bn = nid % gx;

    // staging: issue i covers rows wid*32 + i*8 + (lane>>3); phys slot lane&7.
    // source logical slot = (lane&7) ^ (lane>>3)  (row&7 == lane>>3).
    const int srow  = lane >> 3;                 // 0..7 within an issue
    const int sslot = (lane & 7) ^ srow;         // pre-swizzled source slot
    const u16* pA[4];
    const u16* pB[4];
    #pragma unroll
    for (int i = 0; i < 4; ++i) {
        pA[i] = A  + (size_t)(bm * 128 + wid * 32 + i * 8 + srow) * K + sslot * 8;
        pB[i] = Bt + (size_t)(bn * 128 + wid * 32 + i * 8 + srow) * K + sslot * 8;
    }

    f32x4 acc[4][4] = {};
    const int NT = K >> 6;                        // BK = 64

    #define STAGE(t, b)                                                       \
        do {                                                                  \
            const int _kt = (t) << 6;                                         \
            _Pragma("unroll")                                                 \
            for (int _i = 0; _i < 4; ++_i) {                                  \
                gl2lds16(pA[_i] + _kt, &As[b][(wid * 32 + _i * 8) * 64]);     \
                gl2lds16(pB[_i] + _kt, &Bs[b][(wid * 32 + _i * 8) * 64]);     \
            }                                                                 \
        } while (0)

    STAGE(0, 0);

    for (int t = 0; t < NT; ++t) {
        const int buf = t & 1;
        if (t + 1 < NT) {
            STAGE(t + 1, buf ^ 1);
            asm volatile("s_waitcnt vmcnt(8)" ::: "memory");   // tile t landed
        } else {
            asm volatile("s_waitcnt vmcnt(0)" ::: "memory");
        }
        __builtin_amdgcn_s_barrier();          // tile t visible to all waves
        __builtin_amdgcn_sched_barrier(0);

        #pragma unroll
        for (int kk = 0; kk < 2; ++kk) {
            s16x8 af[4], bf[4];
            #pragma unroll
            for (int m = 0; m < 4; ++m) {
                int rm = wr * 64 + m * 16 + l15;
                int sl = (kk * 4 + l4) ^ (rm & 7);
                af[m] = *(const s16x8*)&As[buf][rm * 64 + sl * 8];
            }
            #pragma unroll
            for (int n = 0; n < 4; ++n) {
                int rn = wc * 64 + n * 16 + l15;
                int sl = (kk * 4 + l4) ^ (rn & 7);
                bf[n] = *(const s16x8*)&Bs[buf][rn * 64 + sl * 8];
            }
            #pragma unroll
            for (int m = 0; m < 4; ++m)
                #pragma unroll
                for (int n = 0; n < 4; ++n)
                    acc[m][n] = __builtin_amdgcn_mfma_f32_16x16x32_bf16(
                        af[m], bf[n], acc[m][n], 0, 0, 0);
        }

        // reads of buf complete before iter t+1 re-stages it
        asm volatile("s_waitcnt lgkmcnt(0)" ::: "memory");
        __builtin_amdgcn_sched_barrier(0);
        __builtin_amdgcn_s_barrier();
    }
    #undef STAGE

    const int grow0 = bm * 128 + wr * 64;
    const int gcol0 = bn * 128 + wc * 64;
    #pragma unroll
    for (int m = 0; m < 4; ++m) {
        #pragma unroll
        for (int n = 0; n < 4; ++n) {
            int col = gcol0 + n * 16 + l15;
            float bz = bias[col];
            #pragma unroll
            for (int r = 0; r < 4; ++r) {
                int row = grow0 + m * 16 + l4 * 4 + r;
                float v = acc[m][n][r] + bz;
                if constexpr (MODE == 0)
                    outb[(size_t)row * N + col] = f2b(v);
                else
                    outf[(size_t)row * N + col] = v;
            }
        }
    }
}

// ---------------------------------------------------------------------------
// Kernel 3: MFMA windowed attention, stageless (verified R7) + T5 setprio.
// ---------------------------------------------------------------------------
__global__ __launch_bounds__(256) void attn_mfma_kernel(
    const u16* __restrict__ qkv, const float* __restrict__ emb4,
    u16* __restrict__ att)
{
    __shared__ __align__(16) u16 P4[4][64 * 72];   // 36864 B
    __shared__ int rowIn[64];
    __shared__ int rowOut[64];

    const int tid  = threadIdx.x;
    const int lane = tid & 63;
    const int wid  = tid >> 6;
    const int l15  = lane & 15, l4 = lane >> 4;

    const int blk = blockIdx.x;
    const int hg  = blk % 3;
    const int win = (blk / 3) & 63;
    const int b   = blk / 192;
    const int bw  = win & 7, bh = win >> 3;
    const int head = hg * 4 + wid;

    if (tid < 64) {                                 // roll(-4,-4) gather LUT
        int pix = tid;
        int gr = (bh * 7 + pix / 7 + 4) % IMG;
        int gc = (bw * 7 + pix % 7 + 4) % IMG;
        rowIn[pix] = (b * IMG + gr) * IMG + gc;
    } else if (tid < 128) {                         // roll(+3,+3) scatter LUT
        int q = tid - 64;
        int fr = (bh * 7 + q / 7 + 3) % IMG;
        int fc = (bw * 7 + q % 7 + 3) % IMG;
        rowOut[q] = (b * IMG + fr) * IMG + fc;
    }
    __syncthreads();

    s16x8 qf[4], kf[4];
    #pragma unroll
    for (int n = 0; n < 4; ++n) {
        int pix = n * 16 + l15;
        size_t base = (size_t)rowIn[pix] * NQKV + head * 32 + l4 * 8;
        qf[n] = *(const s16x8*)(qkv + base);          // Q
        kf[n] = *(const s16x8*)(qkv + base + 384);    // K
    }

    f32x4 sc[4][4] = {};
    __builtin_amdgcn_s_setprio(1);
    #pragma unroll
    for (int m = 0; m < 4; ++m)
        #pragma unroll
        for (int n = 0; n < 4; ++n)
            sc[m][n] = __builtin_amdgcn_mfma_f32_16x16x32_bf16(
                kf[m], qf[n], sc[m][n], 0, 0, 0);
    __builtin_amdgcn_s_setprio(0);

    const float scale = 0.17677669529663687f;        // 1/sqrt(32)
    const float* ev = emb4 + ((bh == 7 ? 1 : 0) + (bw == 7 ? 2 : 0)) * 4096;
    u16* P = P4[wid];
    u32* P32 = (u32*)P;

    #pragma unroll
    for (int n = 0; n < 4; ++n) {
        const int q = n * 16 + l15;
        float vals[4][4];
        float mx = -INFINITY;
        #pragma unroll
        for (int m = 0; m < 4; ++m) {
            float4 e4 = *(const float4*)(ev + q * 64 + m * 16 + l4 * 4);
            #pragma unroll
            for (int r = 0; r < 4; ++r) {
                float v = sc[m][n][r] * scale + ((const float*)&e4)[r];
                vals[m][r] = v;
                mx = fmaxf(mx, v);
            }
        }
        mx = fmaxf(mx, __shfl_xor(mx, 16));
        mx = fmaxf(mx, __shfl_xor(mx, 32));
        float sum = 0.f;
        #pragma unroll
        for (int m = 0; m < 4; ++m)
            #pragma unroll
            for (int r = 0; r < 4; ++r) {
                float p = __expf(vals[m][r] - mx);
                vals[m][r] = p;
                sum += p;
            }
        sum += __shfl_xor(sum, 16);
        sum += __shfl_xor(sum, 32);
        float inv = 1.f / sum;
        #pragma unroll
        for (int m = 0; m < 4; ++m) {
            u32 w0 = (u32)f2b(vals[m][0] * inv) | ((u32)f2b(vals[m][1] * inv) << 16);
            u32 w1 = (u32)f2b(vals[m][2] * inv) | ((u32)f2b(vals[m][3] * inv) << 16);
            int bidx = q * 36 + m * 8 + l4 * 2;
            P32[bidx]     = w0;
            P32[bidx + 1] = w1;
        }
    }
    // per-wave private LDS RAW: compiler inserts lgkmcnt waits; no barrier.

    f32x4 o[4][2] = {};
    #pragma unroll
    for (int kh = 0; kh < 2; ++kh) {
        s16x8 pf[4];
        #pragma unroll
        for (int mq = 0; mq < 4; ++mq)
            pf[mq] = *(const s16x8*)&P[(mq * 16 + l15) * 72 + kh * 32 + l4 * 8];
        s16x8 vf[2];
        #pragma unroll
        for (int ne = 0; ne < 2; ++ne) {
            #pragma unroll
            for (int j = 0; j < 8; ++j) {
                int pix = kh * 32 + l4 * 8 + j;
                vf[ne][j] = (short)qkv[(size_t)rowIn[pix] * NQKV + 768
                                       + head * 32 + ne * 16 + l15];
            }
        }
        __builtin_amdgcn_s_setprio(1);
        #pragma unroll
        for (int mq = 0; mq < 4; ++mq)
            #pragma unroll
            for (int ne = 0; ne < 2; ++ne)
                o[mq][ne] = __builtin_amdgcn_mfma_f32_16x16x32_bf16(
                    pf[mq], vf[ne], o[mq][ne], 0, 0, 0);
        __builtin_amdgcn_s_setprio(0);
    }

    #pragma unroll
    for (int mq = 0; mq < 4; ++mq) {
        #pragma unroll
        for (int r = 0; r < 4; ++r) {
            int q = mq * 16 + l4 * 4 + r;
            if (q < 49) {
                size_t rowb = (size_t)rowOut[q] * DIM + head * 32;
                #pragma unroll
                for (int ne = 0; ne < 2; ++ne)
                    att[rowb + ne * 16 + l15] = f2b(o[mq][ne][r]);
            }
        }
    }
}

// ---------------------------------------------------------------------------
extern "C" void kernel_launch(void* const* d_in, const int* in_sizes, int n_in,
                              void* d_out, int out_size, void* d_ws, size_t ws_size,
                              hipStream_t stream) {
    const float* x     = (const float*)d_in[0];
    const float* w_qkv = (const float*)d_in[1];
    const float* b_qkv = (const float*)d_in[2];
    const float* w_out = (const float*)d_in[3];
    const float* b_out = (const float*)d_in[4];
    float* out = (float*)d_out;

    char* wsp = (char*)d_ws;
    float* emb4  = (float*)wsp;                                  // 64 KB
    u16*   wqkvt = (u16*)(wsp + 65536);                          // [1152][384]
    u16*   woutt = (u16*)(wsp + 65536 + 884736);                 // [384][384]
    float* bqkvp = (float*)(wsp + 65536 + 884736 + 294912);      // [1152]
    const size_t fixed = 65536 + 884736 + 294912 + 4608;         // 1,249,792 B

    // per-batch chunk bytes: xb + qkv + att, all bf16
    const size_t perb = (size_t)ROWS_PER_B * (DIM + NQKV + DIM) * 2; // 12,042,240
    int nb = 16;
    while (nb > 2 && fixed + (size_t)nb * perb > ws_size) nb >>= 1;

    u16* xb   = (u16*)(wsp + fixed);
    u16* qkvb = xb   + (size_t)nb * ROWS_PER_B * DIM;
    u16* attb = qkvb + (size_t)nb * ROWS_PER_B * NQKV;

    emb4_init_kernel<<<16, 256, 0, stream>>>(emb4);
    cvt_transpose_qkv<<<(384 * 1152 + 255) / 256, 256, 0, stream>>>(w_qkv, wqkvt);
    cvt_transpose_bf16<<<(384 * 384 + 255) / 256, 256, 0, stream>>>(w_out, woutt, 384, 384);
    bias_perm_kernel<<<5, 256, 0, stream>>>(b_qkv, bqkvp);

    for (int b0 = 0; b0 < 16; b0 += nb) {
        const int rows = nb * ROWS_PER_B;
        const float* xa = x + (size_t)b0 * ROWS_PER_B * DIM;

        cvt_f32_bf16<<<(rows * DIM / 4 + 255) / 256, 256, 0, stream>>>(
            xa, xb, rows * DIM / 4);

        mfma_gemm<0><<<dim3(NQKV / 128, rows / 128), 256, 0, stream>>>(
            xb, wqkvt, bqkvp, qkvb, nullptr, NQKV, DIM);

        attn_mfma_kernel<<<nb * 192, 256, 0, stream>>>(qkvb, emb4, attb);

        mfma_gemm<1><<<dim3(DIM / 128, rows / 128), 256, 0, stream>>>(
            attb, woutt, b_out, nullptr, out + (size_t)b0 * ROWS_PER_B * DIM, DIM, DIM);
    }
}

// Round 16
// 177.022 us; speedup vs baseline: 1.1551x; 1.0076x over previous
//
#include <hip/hip_runtime.h>
#include <math.h>

// Problem constants
#define DIM   384
#define NQKV  1152
#define IMG   56
#define ROWS_PER_B (IMG*IMG)           // 3136 pixels per batch image

typedef unsigned short u16;
typedef unsigned int u32;
typedef __attribute__((ext_vector_type(4))) float f32x4;
typedef __attribute__((ext_vector_type(8))) short s16x8;

__device__ __forceinline__ u16 f2b(float f) {           // fp32 -> bf16 RNE
    unsigned u = __float_as_uint(f);
    return (u16)((u + 0x7fffu + ((u >> 16) & 1u)) >> 16);
}

// async global->LDS, 16B/lane, dest = wave-uniform base + lane*16
__device__ __forceinline__ void gl2lds16(const void* g, void* l) {
    __builtin_amdgcn_global_load_lds(
        (const __attribute__((address_space(1))) void*)g,
        (__attribute__((address_space(3))) void*)l, 16, 0, 0);
}

// ---------------------------------------------------------------------------
// Kernel 1: masked relative-embedding table, 4 variants [4][64][64].
// Sinusoid math bit-faithful to numpy arange fill (verified R3). DO NOT TOUCH.
// ---------------------------------------------------------------------------
__global__ __launch_bounds__(256) void emb4_init_kernel(float* __restrict__ emb4) {
    int idx = blockIdx.x * 256 + threadIdx.x;
    if (idx >= 64 * 64) return;
    int q = idx >> 6, k = idx & 63;

    bool pad = (q >= 49) || (k >= 49);
    float base = 0.f;
    if (!pad) {
        const double step  = 1.0 / 7.0;
        const double delta = __dsub_rn(__dadd_rn(1.0, step), 1.0);
        double xk = __dadd_rn(1.0, __dmul_rn((double)k, delta));
        double xq = __dadd_rn(1.0, __dmul_rn((double)q, delta));
        int xi = (int)__dsub_rn(xk, xq);
        int yi = (k % 7) - (q % 7);
        int r = xi % 13; if (r < 0) r += 13;
        int c = yi % 13; if (c < 0) c += 13;
        const float scl = (float)(-0.7084877209212449);  // -log(10000)/13
        if ((c & 1) == 0) base = sinf((float)r * expf((float)c * scl));
        else              base = cosf((float)r * expf((float)(c - 1) * scl));
    }
    bool rmask = !pad && ((q >= 28) != (k >= 28));
    bool cmask = !pad && ((q % 7 >= 4) != (k % 7 >= 4));
    #pragma unroll
    for (int v = 0; v < 4; ++v) {
        float val = base;
        if (pad || ((v & 1) && rmask) || ((v & 2) && cmask)) val = -INFINITY;
        emb4[v * 4096 + idx] = val;
    }
}

// ---------------------------------------------------------------------------
// Conversion kernels
// ---------------------------------------------------------------------------
__global__ __launch_bounds__(256) void cvt_f32_bf16(
    const float* __restrict__ in, u16* __restrict__ out, int n4) {
    int i = blockIdx.x * 256 + threadIdx.x;
    if (i >= n4) return;
    float4 v = ((const float4*)in)[i];
    ushort4 o;
    o.x = f2b(v.x); o.y = f2b(v.y); o.z = f2b(v.z); o.w = f2b(v.w);
    ((ushort4*)out)[i] = o;
}

__global__ __launch_bounds__(256) void cvt_transpose_bf16(
    const float* __restrict__ w, u16* __restrict__ wt, int R, int C) {
    int i = blockIdx.x * 256 + threadIdx.x;
    if (i >= R * C) return;
    int r = i / C, c = i % C;
    wt[(size_t)c * R + r] = f2b(w[i]);
}

// QKV transpose with de-interleaving row permutation: GEMM col n' = comp*384+ch
__global__ __launch_bounds__(256) void cvt_transpose_qkv(
    const float* __restrict__ w, u16* __restrict__ wt) {
    int i = blockIdx.x * 256 + threadIdx.x;
    if (i >= 384 * 1152) return;
    int k = i / 1152, col = i % 1152;
    int ch = col / 3, comp = col % 3;
    int np = comp * 384 + ch;
    wt[(size_t)np * 384 + k] = f2b(w[i]);
}

__global__ __launch_bounds__(256) void bias_perm_kernel(
    const float* __restrict__ b, float* __restrict__ bp) {
    int n = blockIdx.x * 256 + threadIdx.x;
    if (n >= 1152) return;
    int comp = n / 384, ch = n % 384;
    bp[n] = b[ch * 3 + comp];
}

// ---------------------------------------------------------------------------
// MFMA bf16 GEMM: C[M][N] = A[M][K] @ Bt[N][K]^T + bias.
// 128x128 tile, BK=64 (R15-verified: 86->80.6us), 4 waves, 2 k-subtiles/step.
// LDS [128][64] bf16 x2 operands x2 dbuf = 64KB. Rule-21 both-sides swizzle:
// phys slot8 = logical ^ (row&7); inverse folded into gload source slot.
// Counted vmcnt dbuf: 8 issues/wave/tile; vmcnt(8) waits exactly tile t.
// NEW: trailing lgkm-drain+barrier elided on the LAST iteration (epilogue is
// LDS-free, so the read-before-overwrite guard is not needed after t=NT-1).
// Grid: bijective XCD remap (m204, R8-verified: FETCH 167->22 MB).
// MODE 0: bf16 out (QKV). MODE 1: fp32 out (final projection).
// ---------------------------------------------------------------------------
template <int MODE>
__global__ __launch_bounds__(256) void mfma_gemm(
    const u16* __restrict__ A, const u16* __restrict__ Bt,
    const float* __restrict__ bias,
    u16* __restrict__ outb, float* __restrict__ outf,
    int N, int K)
{
    __shared__ __align__(16) u16 As[2][8192];   // [128][64] swizzled
    __shared__ __align__(16) u16 Bs[2][8192];

    const int tid  = threadIdx.x;
    const int lane = tid & 63;
    const int wid  = tid >> 6;
    const int wr   = wid >> 1, wc = wid & 1;
    const int l15  = lane & 15, l4 = lane >> 4;

    // bijective XCD remap (m204): contiguous chunk of blocks per XCD
    const int gx  = gridDim.x;
    const int nwg = gx * gridDim.y;
    int wg  = blockIdx.y * gx + blockIdx.x;
    int q8  = nwg >> 3, r8 = nwg & 7;
    int xcd = wg & 7, idx = wg >> 3;
    int nid = (xcd < r8 ? xcd * (q8 + 1) : r8 * (q8 + 1) + (xcd - r8) * q8) + idx;
    const int bm = nid / gx, bn = nid % gx;

    // staging: issue i covers rows wid*32 + i*8 + (lane>>3); phys slot lane&7.
    // source logical slot = (lane&7) ^ (lane>>3)  (row&7 == lane>>3).
    const int srow  = lane >> 3;                 // 0..7 within an issue
    const int sslot = (lane & 7) ^ srow;         // pre-swizzled source slot
    const u16* pA[4];
    const u16* pB[4];
    #pragma unroll
    for (int i = 0; i < 4; ++i) {
        pA[i] = A  + (size_t)(bm * 128 + wid * 32 + i * 8 + srow) * K + sslot * 8;
        pB[i] = Bt + (size_t)(bn * 128 + wid * 32 + i * 8 + srow) * K + sslot * 8;
    }

    f32x4 acc[4][4] = {};
    const int NT = K >> 6;                        // BK = 64

    #define STAGE(t, b)                                                       \
        do {                                                                  \
            const int _kt = (t) << 6;                                         \
            _Pragma("unroll")                                                 \
            for (int _i = 0; _i < 4; ++_i) {                                  \
                gl2lds16(pA[_i] + _kt, &As[b][(wid * 32 + _i * 8) * 64]);     \
                gl2lds16(pB[_i] + _kt, &Bs[b][(wid * 32 + _i * 8) * 64]);     \
            }                                                                 \
        } while (0)

    STAGE(0, 0);

    for (int t = 0; t < NT; ++t) {
        const int buf = t & 1;
        if (t + 1 < NT) {
            STAGE(t + 1, buf ^ 1);
            asm volatile("s_waitcnt vmcnt(8)" ::: "memory");   // tile t landed
        } else {
            asm volatile("s_waitcnt vmcnt(0)" ::: "memory");
        }
        __builtin_amdgcn_s_barrier();          // tile t visible to all waves
        __builtin_amdgcn_sched_barrier(0);

        #pragma unroll
        for (int kk = 0; kk < 2; ++kk) {
            s16x8 af[4], bf[4];
            #pragma unroll
            for (int m = 0; m < 4; ++m) {
                int rm = wr * 64 + m * 16 + l15;
                int sl = (kk * 4 + l4) ^ (rm & 7);
                af[m] = *(const s16x8*)&As[buf][rm * 64 + sl * 8];
            }
            #pragma unroll
            for (int n = 0; n < 4; ++n) {
                int rn = wc * 64 + n * 16 + l15;
                int sl = (kk * 4 + l4) ^ (rn & 7);
                bf[n] = *(const s16x8*)&Bs[buf][rn * 64 + sl * 8];
            }
            #pragma unroll
            for (int m = 0; m < 4; ++m)
                #pragma unroll
                for (int n = 0; n < 4; ++n)
                    acc[m][n] = __builtin_amdgcn_mfma_f32_16x16x32_bf16(
                        af[m], bf[n], acc[m][n], 0, 0, 0);
        }

        // reads of buf must complete before iter t+1 re-stages it — but only
        // if there IS an iter t+1 (epilogue never touches LDS).
        if (t + 1 < NT) {
            asm volatile("s_waitcnt lgkmcnt(0)" ::: "memory");
            __builtin_amdgcn_sched_barrier(0);
            __builtin_amdgcn_s_barrier();
        }
    }
    #undef STAGE

    const int grow0 = bm * 128 + wr * 64;
    const int gcol0 = bn * 128 + wc * 64;
    #pragma unroll
    for (int m = 0; m < 4; ++m) {
        #pragma unroll
        for (int n = 0; n < 4; ++n) {
            int col = gcol0 + n * 16 + l15;
            float bz = bias[col];
            #pragma unroll
            for (int r = 0; r < 4; ++r) {
                int row = grow0 + m * 16 + l4 * 4 + r;
                float v = acc[m][n][r] + bz;
                if constexpr (MODE == 0)
                    outb[(size_t)row * N + col] = f2b(v);
                else
                    outf[(size_t)row * N + col] = v;
            }
        }
    }
}

// ---------------------------------------------------------------------------
// Kernel 3: MFMA windowed attention, stageless (verified R7) + T5 setprio.
// NEW (T14 issue-early): V fragment loads hoisted to the TOP of the kernel,
// issued together with Q/K — their ~900-cyc global latency hides under
// QK^T + softmax instead of being exposed after the P write.
// ---------------------------------------------------------------------------
__global__ __launch_bounds__(256) void attn_mfma_kernel(
    const u16* __restrict__ qkv, const float* __restrict__ emb4,
    u16* __restrict__ att)
{
    __shared__ __align__(16) u16 P4[4][64 * 72];   // 36864 B
    __shared__ int rowIn[64];
    __shared__ int rowOut[64];

    const int tid  = threadIdx.x;
    const int lane = tid & 63;
    const int wid  = tid >> 6;
    const int l15  = lane & 15, l4 = lane >> 4;

    const int blk = blockIdx.x;
    const int hg  = blk % 3;
    const int win = (blk / 3) & 63;
    const int b   = blk / 192;
    const int bw  = win & 7, bh = win >> 3;
    const int head = hg * 4 + wid;

    if (tid < 64) {                                 // roll(-4,-4) gather LUT
        int pix = tid;
        int gr = (bh * 7 + pix / 7 + 4) % IMG;
        int gc = (bw * 7 + pix % 7 + 4) % IMG;
        rowIn[pix] = (b * IMG + gr) * IMG + gc;
    } else if (tid < 128) {                         // roll(+3,+3) scatter LUT
        int q = tid - 64;
        int fr = (bh * 7 + q / 7 + 3) % IMG;
        int fc = (bw * 7 + q % 7 + 3) % IMG;
        rowOut[q] = (b * IMG + fr) * IMG + fc;
    }
    __syncthreads();

    // ---- issue ALL global loads up front (Q, K fragments + V fragments) ----
    s16x8 qf[4], kf[4];
    #pragma unroll
    for (int n = 0; n < 4; ++n) {
        int pix = n * 16 + l15;
        size_t base = (size_t)rowIn[pix] * NQKV + head * 32 + l4 * 8;
        qf[n] = *(const s16x8*)(qkv + base);          // Q
        kf[n] = *(const s16x8*)(qkv + base + 384);    // K
    }
    s16x8 vf[2][2];                                   // [kh][ne], +16 VGPR
    #pragma unroll
    for (int kh = 0; kh < 2; ++kh)
        #pragma unroll
        for (int ne = 0; ne < 2; ++ne)
            #pragma unroll
            for (int j = 0; j < 8; ++j) {
                int pix = kh * 32 + l4 * 8 + j;
                vf[kh][ne][j] = (short)qkv[(size_t)rowIn[pix] * NQKV + 768
                                           + head * 32 + ne * 16 + l15];
            }

    f32x4 sc[4][4] = {};
    __builtin_amdgcn_s_setprio(1);
    #pragma unroll
    for (int m = 0; m < 4; ++m)
        #pragma unroll
        for (int n = 0; n < 4; ++n)
            sc[m][n] = __builtin_amdgcn_mfma_f32_16x16x32_bf16(
                kf[m], qf[n], sc[m][n], 0, 0, 0);
    __builtin_amdgcn_s_setprio(0);

    const float scale = 0.17677669529663687f;        // 1/sqrt(32)
    const float* ev = emb4 + ((bh == 7 ? 1 : 0) + (bw == 7 ? 2 : 0)) * 4096;
    u16* P = P4[wid];
    u32* P32 = (u32*)P;

    #pragma unroll
    for (int n = 0; n < 4; ++n) {
        const int q = n * 16 + l15;
        float vals[4][4];
        float mx = -INFINITY;
        #pragma unroll
        for (int m = 0; m < 4; ++m) {
            float4 e4 = *(const float4*)(ev + q * 64 + m * 16 + l4 * 4);
            #pragma unroll
            for (int r = 0; r < 4; ++r) {
                float v = sc[m][n][r] * scale + ((const float*)&e4)[r];
                vals[m][r] = v;
                mx = fmaxf(mx, v);
            }
        }
        mx = fmaxf(mx, __shfl_xor(mx, 16));
        mx = fmaxf(mx, __shfl_xor(mx, 32));
        float sum = 0.f;
        #pragma unroll
        for (int m = 0; m < 4; ++m)
            #pragma unroll
            for (int r = 0; r < 4; ++r) {
                float p = __expf(vals[m][r] - mx);
                vals[m][r] = p;
                sum += p;
            }
        sum += __shfl_xor(sum, 16);
        sum += __shfl_xor(sum, 32);
        float inv = 1.f / sum;
        #pragma unroll
        for (int m = 0; m < 4; ++m) {
            u32 w0 = (u32)f2b(vals[m][0] * inv) | ((u32)f2b(vals[m][1] * inv) << 16);
            u32 w1 = (u32)f2b(vals[m][2] * inv) | ((u32)f2b(vals[m][3] * inv) << 16);
            int bidx = q * 36 + m * 8 + l4 * 2;
            P32[bidx]     = w0;
            P32[bidx + 1] = w1;
        }
    }
    // per-wave private LDS RAW: compiler inserts lgkmcnt waits; no barrier.

    f32x4 o[4][2] = {};
    #pragma unroll
    for (int kh = 0; kh < 2; ++kh) {
        s16x8 pf[4];
        #pragma unroll
        for (int mq = 0; mq < 4; ++mq)
            pf[mq] = *(const s16x8*)&P[(mq * 16 + l15) * 72 + kh * 32 + l4 * 8];
        __builtin_amdgcn_s_setprio(1);
        #pragma unroll
        for (int mq = 0; mq < 4; ++mq)
            #pragma unroll
            for (int ne = 0; ne < 2; ++ne)
                o[mq][ne] = __builtin_amdgcn_mfma_f32_16x16x32_bf16(
                    pf[mq], vf[kh][ne], o[mq][ne], 0, 0, 0);
        __builtin_amdgcn_s_setprio(0);
    }

    #pragma unroll
    for (int mq = 0; mq < 4; ++mq) {
        #pragma unroll
        for (int r = 0; r < 4; ++r) {
            int q = mq * 16 + l4 * 4 + r;
            if (q < 49) {
                size_t rowb = (size_t)rowOut[q] * DIM + head * 32;
                #pragma unroll
                for (int ne = 0; ne < 2; ++ne)
                    att[rowb + ne * 16 + l15] = f2b(o[mq][ne][r]);
            }
        }
    }
}

// ---------------------------------------------------------------------------
extern "C" void kernel_launch(void* const* d_in, const int* in_sizes, int n_in,
                              void* d_out, int out_size, void* d_ws, size_t ws_size,
                              hipStream_t stream) {
    const float* x     = (const float*)d_in[0];
    const float* w_qkv = (const float*)d_in[1];
    const float* b_qkv = (const float*)d_in[2];
    const float* w_out = (const float*)d_in[3];
    const float* b_out = (const float*)d_in[4];
    float* out = (float*)d_out;

    char* wsp = (char*)d_ws;
    float* emb4  = (float*)wsp;                                  // 64 KB
    u16*   wqkvt = (u16*)(wsp + 65536);                          // [1152][384]
    u16*   woutt = (u16*)(wsp + 65536 + 884736);                 // [384][384]
    float* bqkvp = (float*)(wsp + 65536 + 884736 + 294912);      // [1152]
    const size_t fixed = 65536 + 884736 + 294912 + 4608;         // 1,249,792 B

    // per-batch chunk bytes: xb + qkv + att, all bf16
    const size_t perb = (size_t)ROWS_PER_B * (DIM + NQKV + DIM) * 2; // 12,042,240
    int nb = 16;
    while (nb > 2 && fixed + (size_t)nb * perb > ws_size) nb >>= 1;

    u16* xb   = (u16*)(wsp + fixed);
    u16* qkvb = xb   + (size_t)nb * ROWS_PER_B * DIM;
    u16* attb = qkvb + (size_t)nb * ROWS_PER_B * NQKV;

    emb4_init_kernel<<<16, 256, 0, stream>>>(emb4);
    cvt_transpose_qkv<<<(384 * 1152 + 255) / 256, 256, 0, stream>>>(w_qkv, wqkvt);
    cvt_transpose_bf16<<<(384 * 384 + 255) / 256, 256, 0, stream>>>(w_out, woutt, 384, 384);
    bias_perm_kernel<<<5, 256, 0, stream>>>(b_qkv, bqkvp);

    for (int b0 = 0; b0 < 16; b0 += nb) {
        const int rows = nb * ROWS_PER_B;
        const float* xa = x + (size_t)b0 * ROWS_PER_B * DIM;

        cvt_f32_bf16<<<(rows * DIM / 4 + 255) / 256, 256, 0, stream>>>(
            xa, xb, rows * DIM / 4);

        mfma_gemm<0><<<dim3(NQKV / 128, rows / 128), 256, 0, stream>>>(
            xb, wqkvt, bqkvp, qkvb, nullptr, NQKV, DIM);

        attn_mfma_kernel<<<nb * 192, 256, 0, stream>>>(qkvb, emb4, attb);

        mfma_gemm<1><<<dim3(DIM / 128, rows / 128), 256, 0, stream>>>(
            attb, woutt, b_out, nullptr, out + (size_t)b0 * ROWS_PER_B * DIM, DIM, DIM);
    }
}

// Round 17
// 163.649 us; speedup vs baseline: 1.2495x; 1.0817x over previous
//
#include <hip/hip_runtime.h>
#include <math.h>

// Problem constants
#define DIM   384
#define NQKV  1152
#define IMG   56
#define ROWS_PER_B (IMG*IMG)           // 3136 pixels per batch image

typedef unsigned short u16;
typedef unsigned int u32;
typedef __attribute__((ext_vector_type(4))) float f32x4;
typedef __attribute__((ext_vector_type(8))) short s16x8;

__device__ __forceinline__ u16 f2b(float f) {           // fp32 -> bf16 RNE
    unsigned u = __float_as_uint(f);
    return (u16)((u + 0x7fffu + ((u >> 16) & 1u)) >> 16);
}

// async global->LDS, 16B/lane, dest = wave-uniform base + lane*16
__device__ __forceinline__ void gl2lds16(const void* g, void* l) {
    __builtin_amdgcn_global_load_lds(
        (const __attribute__((address_space(1))) void*)g,
        (__attribute__((address_space(3))) void*)l, 16, 0, 0);
}

// ---------------------------------------------------------------------------
// Kernel 1: masked relative-embedding table, 4 variants [4][64][64].
// Sinusoid math bit-faithful to numpy arange fill (verified R3). DO NOT TOUCH.
// ---------------------------------------------------------------------------
__global__ __launch_bounds__(256) void emb4_init_kernel(float* __restrict__ emb4) {
    int idx = blockIdx.x * 256 + threadIdx.x;
    if (idx >= 64 * 64) return;
    int q = idx >> 6, k = idx & 63;

    bool pad = (q >= 49) || (k >= 49);
    float base = 0.f;
    if (!pad) {
        const double step  = 1.0 / 7.0;
        const double delta = __dsub_rn(__dadd_rn(1.0, step), 1.0);
        double xk = __dadd_rn(1.0, __dmul_rn((double)k, delta));
        double xq = __dadd_rn(1.0, __dmul_rn((double)q, delta));
        int xi = (int)__dsub_rn(xk, xq);
        int yi = (k % 7) - (q % 7);
        int r = xi % 13; if (r < 0) r += 13;
        int c = yi % 13; if (c < 0) c += 13;
        const float scl = (float)(-0.7084877209212449);  // -log(10000)/13
        if ((c & 1) == 0) base = sinf((float)r * expf((float)c * scl));
        else              base = cosf((float)r * expf((float)(c - 1) * scl));
    }
    bool rmask = !pad && ((q >= 28) != (k >= 28));
    bool cmask = !pad && ((q % 7 >= 4) != (k % 7 >= 4));
    #pragma unroll
    for (int v = 0; v < 4; ++v) {
        float val = base;
        if (pad || ((v & 1) && rmask) || ((v & 2) && cmask)) val = -INFINITY;
        emb4[v * 4096 + idx] = val;
    }
}

// ---------------------------------------------------------------------------
// Conversion kernels
// ---------------------------------------------------------------------------
__global__ __launch_bounds__(256) void cvt_f32_bf16(
    const float* __restrict__ in, u16* __restrict__ out, int n4) {
    int i = blockIdx.x * 256 + threadIdx.x;
    if (i >= n4) return;
    float4 v = ((const float4*)in)[i];
    ushort4 o;
    o.x = f2b(v.x); o.y = f2b(v.y); o.z = f2b(v.z); o.w = f2b(v.w);
    ((ushort4*)out)[i] = o;
}

__global__ __launch_bounds__(256) void cvt_transpose_bf16(
    const float* __restrict__ w, u16* __restrict__ wt, int R, int C) {
    int i = blockIdx.x * 256 + threadIdx.x;
    if (i >= R * C) return;
    int r = i / C, c = i % C;
    wt[(size_t)c * R + r] = f2b(w[i]);
}

// QKV transpose with de-interleaving row permutation: GEMM col n' = comp*384+ch
__global__ __launch_bounds__(256) void cvt_transpose_qkv(
    const float* __restrict__ w, u16* __restrict__ wt) {
    int i = blockIdx.x * 256 + threadIdx.x;
    if (i >= 384 * 1152) return;
    int k = i / 1152, col = i % 1152;
    int ch = col / 3, comp = col % 3;
    int np = comp * 384 + ch;
    wt[(size_t)np * 384 + k] = f2b(w[i]);
}

__global__ __launch_bounds__(256) void bias_perm_kernel(
    const float* __restrict__ b, float* __restrict__ bp) {
    int n = blockIdx.x * 256 + threadIdx.x;
    if (n >= 1152) return;
    int comp = n / 384, ch = n % 384;
    bp[n] = b[ch * 3 + comp];
}

// ---------------------------------------------------------------------------
// MFMA bf16 GEMM: C[M][N] = A[M][K] @ Bt[N][K]^T + bias.
// 128x128 tile, BK=64 (R15-verified), 4 waves, 2 k-subtiles/step.
// NEW: asymmetric buffering to cut LDS 64->48 KB (3 blocks/CU, 12 waves —
// registers 88V+64A=152 allow 3 waves/SIMD; LDS was the binding cap at 2):
//   A double-buffered (2 x 16 KB), B SINGLE-buffered (16 KB).
// Per-step chain (per-wave vmcnt ledger): top: STAGE_A(t+1) -> vmcnt(4)
// [in-order completion => A(t),B(t) landed; A(t+1) in flight] -> barrier
// [all waves' tiles landed] -> ds_read+MFMA(t) -> lgkm(0)+barrier [all B
// reads retired] -> STAGE_B(t+1) [safe overwrite; lands before next top's
// vmcnt(4) releases]. Last iter: vmcnt(0), drains elided (epilogue LDS-free).
// Rule-21 both-sides swizzle (R8-verified 0 conflicts): phys slot8 =
// logical ^ (row&7); inverse folded into gload source slot.
// Grid: bijective XCD remap (m204, R8-verified: FETCH 167->22 MB).
// MODE 0: bf16 out (QKV). MODE 1: fp32 out (final projection).
// ---------------------------------------------------------------------------
template <int MODE>
__global__ __launch_bounds__(256) void mfma_gemm(
    const u16* __restrict__ A, const u16* __restrict__ Bt,
    const float* __restrict__ bias,
    u16* __restrict__ outb, float* __restrict__ outf,
    int N, int K)
{
    __shared__ __align__(16) u16 As[2][8192];   // [128][64] swizzled, dbuf
    __shared__ __align__(16) u16 Bs[8192];      // [128][64] swizzled, single

    const int tid  = threadIdx.x;
    const int lane = tid & 63;
    const int wid  = tid >> 6;
    const int wr   = wid >> 1, wc = wid & 1;
    const int l15  = lane & 15, l4 = lane >> 4;

    // bijective XCD remap (m204): contiguous chunk of blocks per XCD
    const int gx  = gridDim.x;
    const int nwg = gx * gridDim.y;
    int wg  = blockIdx.y * gx + blockIdx.x;
    int q8  = nwg >> 3, r8 = nwg & 7;
    int xcd = wg & 7, idx = wg >> 3;
    int nid = (xcd < r8 ? xcd * (q8 + 1) : r8 * (q8 + 1) + (xcd - r8) * q8) + idx;
    const int bm = nid / gx, bn = nid % gx;

    // staging: issue i covers rows wid*32 + i*8 + (lane>>3); phys slot lane&7.
    // source logical slot = (lane&7) ^ (lane>>3)  (row&7 == lane>>3).
    const int srow  = lane >> 3;                 // 0..7 within an issue
    const int sslot = (lane & 7) ^ srow;         // pre-swizzled source slot
    const u16* pA[4];
    const u16* pB[4];
    #pragma unroll
    for (int i = 0; i < 4; ++i) {
        pA[i] = A  + (size_t)(bm * 128 + wid * 32 + i * 8 + srow) * K + sslot * 8;
        pB[i] = Bt + (size_t)(bn * 128 + wid * 32 + i * 8 + srow) * K + sslot * 8;
    }

    f32x4 acc[4][4] = {};
    const int NT = K >> 6;                        // BK = 64

    #define STAGE_A(t, b)                                                     \
        do {                                                                  \
            const int _kt = (t) << 6;                                         \
            _Pragma("unroll")                                                 \
            for (int _i = 0; _i < 4; ++_i)                                    \
                gl2lds16(pA[_i] + _kt, &As[b][(wid * 32 + _i * 8) * 64]);     \
        } while (0)
    #define STAGE_B(t)                                                        \
        do {                                                                  \
            const int _kt = (t) << 6;                                         \
            _Pragma("unroll")                                                 \
            for (int _i = 0; _i < 4; ++_i)                                    \
                gl2lds16(pB[_i] + _kt, &Bs[(wid * 32 + _i * 8) * 64]);        \
        } while (0)

    STAGE_A(0, 0);
    STAGE_B(0);

    for (int t = 0; t < NT; ++t) {
        const int buf = t & 1;
        if (t + 1 < NT) {
            STAGE_A(t + 1, buf ^ 1);
            // in-order: A(t) -> B(t) -> A(t+1); leave A(t+1)'s 4 in flight
            asm volatile("s_waitcnt vmcnt(4)" ::: "memory");
        } else {
            asm volatile("s_waitcnt vmcnt(0)" ::: "memory");
        }
        __builtin_amdgcn_s_barrier();          // tile t visible to all waves
        __builtin_amdgcn_sched_barrier(0);

        #pragma unroll
        for (int kk = 0; kk < 2; ++kk) {
            s16x8 af[4], bf[4];
            #pragma unroll
            for (int m = 0; m < 4; ++m) {
                int rm = wr * 64 + m * 16 + l15;
                int sl = (kk * 4 + l4) ^ (rm & 7);
                af[m] = *(const s16x8*)&As[buf][rm * 64 + sl * 8];
            }
            #pragma unroll
            for (int n = 0; n < 4; ++n) {
                int rn = wc * 64 + n * 16 + l15;
                int sl = (kk * 4 + l4) ^ (rn & 7);
                bf[n] = *(const s16x8*)&Bs[rn * 64 + sl * 8];
            }
            #pragma unroll
            for (int m = 0; m < 4; ++m)
                #pragma unroll
                for (int n = 0; n < 4; ++n)
                    acc[m][n] = __builtin_amdgcn_mfma_f32_16x16x32_bf16(
                        af[m], bf[n], acc[m][n], 0, 0, 0);
        }

        if (t + 1 < NT) {
            // all waves' reads of Bs (and As[buf]) retired before new B lands
            asm volatile("s_waitcnt lgkmcnt(0)" ::: "memory");
            __builtin_amdgcn_sched_barrier(0);
            __builtin_amdgcn_s_barrier();
            STAGE_B(t + 1);                     // safe overwrite of Bs
        }
    }
    #undef STAGE_A
    #undef STAGE_B

    const int grow0 = bm * 128 + wr * 64;
    const int gcol0 = bn * 128 + wc * 64;
    #pragma unroll
    for (int m = 0; m < 4; ++m) {
        #pragma unroll
        for (int n = 0; n < 4; ++n) {
            int col = gcol0 + n * 16 + l15;
            float bz = bias[col];
            #pragma unroll
            for (int r = 0; r < 4; ++r) {
                int row = grow0 + m * 16 + l4 * 4 + r;
                float v = acc[m][n][r] + bz;
                if constexpr (MODE == 0)
                    outb[(size_t)row * N + col] = f2b(v);
                else
                    outf[(size_t)row * N + col] = v;
            }
        }
    }
}

// ---------------------------------------------------------------------------
// Kernel 3: MFMA windowed attention, stageless (verified R7) + T5 setprio +
// T14 issue-early V loads (R16).
// ---------------------------------------------------------------------------
__global__ __launch_bounds__(256) void attn_mfma_kernel(
    const u16* __restrict__ qkv, const float* __restrict__ emb4,
    u16* __restrict__ att)
{
    __shared__ __align__(16) u16 P4[4][64 * 72];   // 36864 B
    __shared__ int rowIn[64];
    __shared__ int rowOut[64];

    const int tid  = threadIdx.x;
    const int lane = tid & 63;
    const int wid  = tid >> 6;
    const int l15  = lane & 15, l4 = lane >> 4;

    const int blk = blockIdx.x;
    const int hg  = blk % 3;
    const int win = (blk / 3) & 63;
    const int b   = blk / 192;
    const int bw  = win & 7, bh = win >> 3;
    const int head = hg * 4 + wid;

    if (tid < 64) {                                 // roll(-4,-4) gather LUT
        int pix = tid;
        int gr = (bh * 7 + pix / 7 + 4) % IMG;
        int gc = (bw * 7 + pix % 7 + 4) % IMG;
        rowIn[pix] = (b * IMG + gr) * IMG + gc;
    } else if (tid < 128) {                         // roll(+3,+3) scatter LUT
        int q = tid - 64;
        int fr = (bh * 7 + q / 7 + 3) % IMG;
        int fc = (bw * 7 + q % 7 + 3) % IMG;
        rowOut[q] = (b * IMG + fr) * IMG + fc;
    }
    __syncthreads();

    // ---- issue ALL global loads up front (Q, K fragments + V fragments) ----
    s16x8 qf[4], kf[4];
    #pragma unroll
    for (int n = 0; n < 4; ++n) {
        int pix = n * 16 + l15;
        size_t base = (size_t)rowIn[pix] * NQKV + head * 32 + l4 * 8;
        qf[n] = *(const s16x8*)(qkv + base);          // Q
        kf[n] = *(const s16x8*)(qkv + base + 384);    // K
    }
    s16x8 vf[2][2];                                   // [kh][ne], +16 VGPR
    #pragma unroll
    for (int kh = 0; kh < 2; ++kh)
        #pragma unroll
        for (int ne = 0; ne < 2; ++ne)
            #pragma unroll
            for (int j = 0; j < 8; ++j) {
                int pix = kh * 32 + l4 * 8 + j;
                vf[kh][ne][j] = (short)qkv[(size_t)rowIn[pix] * NQKV + 768
                                           + head * 32 + ne * 16 + l15];
            }

    f32x4 sc[4][4] = {};
    __builtin_amdgcn_s_setprio(1);
    #pragma unroll
    for (int m = 0; m < 4; ++m)
        #pragma unroll
        for (int n = 0; n < 4; ++n)
            sc[m][n] = __builtin_amdgcn_mfma_f32_16x16x32_bf16(
                kf[m], qf[n], sc[m][n], 0, 0, 0);
    __builtin_amdgcn_s_setprio(0);

    const float scale = 0.17677669529663687f;        // 1/sqrt(32)
    const float* ev = emb4 + ((bh == 7 ? 1 : 0) + (bw == 7 ? 2 : 0)) * 4096;
    u16* P = P4[wid];
    u32* P32 = (u32*)P;

    #pragma unroll
    for (int n = 0; n < 4; ++n) {
        const int q = n * 16 + l15;
        float vals[4][4];
        float mx = -INFINITY;
        #pragma unroll
        for (int m = 0; m < 4; ++m) {
            float4 e4 = *(const float4*)(ev + q * 64 + m * 16 + l4 * 4);
            #pragma unroll
            for (int r = 0; r < 4; ++r) {
                float v = sc[m][n][r] * scale + ((const float*)&e4)[r];
                vals[m][r] = v;
                mx = fmaxf(mx, v);
            }
        }
        mx = fmaxf(mx, __shfl_xor(mx, 16));
        mx = fmaxf(mx, __shfl_xor(mx, 32));
        float sum = 0.f;
        #pragma unroll
        for (int m = 0; m < 4; ++m)
            #pragma unroll
            for (int r = 0; r < 4; ++r) {
                float p = __expf(vals[m][r] - mx);
                vals[m][r] = p;
                sum += p;
            }
        sum += __shfl_xor(sum, 16);
        sum += __shfl_xor(sum, 32);
        float inv = 1.f / sum;
        #pragma unroll
        for (int m = 0; m < 4; ++m) {
            u32 w0 = (u32)f2b(vals[m][0] * inv) | ((u32)f2b(vals[m][1] * inv) << 16);
            u32 w1 = (u32)f2b(vals[m][2] * inv) | ((u32)f2b(vals[m][3] * inv) << 16);
            int bidx = q * 36 + m * 8 + l4 * 2;
            P32[bidx]     = w0;
            P32[bidx + 1] = w1;
        }
    }
    // per-wave private LDS RAW: compiler inserts lgkmcnt waits; no barrier.

    f32x4 o[4][2] = {};
    #pragma unroll
    for (int kh = 0; kh < 2; ++kh) {
        s16x8 pf[4];
        #pragma unroll
        for (int mq = 0; mq < 4; ++mq)
            pf[mq] = *(const s16x8*)&P[(mq * 16 + l15) * 72 + kh * 32 + l4 * 8];
        __builtin_amdgcn_s_setprio(1);
        #pragma unroll
        for (int mq = 0; mq < 4; ++mq)
            #pragma unroll
            for (int ne = 0; ne < 2; ++ne)
                o[mq][ne] = __builtin_amdgcn_mfma_f32_16x16x32_bf16(
                    pf[mq], vf[kh][ne], o[mq][ne], 0, 0, 0);
        __builtin_amdgcn_s_setprio(0);
    }

    #pragma unroll
    for (int mq = 0; mq < 4; ++mq) {
        #pragma unroll
        for (int r = 0; r < 4; ++r) {
            int q = mq * 16 + l4 * 4 + r;
            if (q < 49) {
                size_t rowb = (size_t)rowOut[q] * DIM + head * 32;
                #pragma unroll
                for (int ne = 0; ne < 2; ++ne)
                    att[rowb + ne * 16 + l15] = f2b(o[mq][ne][r]);
            }
        }
    }
}

// ---------------------------------------------------------------------------
extern "C" void kernel_launch(void* const* d_in, const int* in_sizes, int n_in,
                              void* d_out, int out_size, void* d_ws, size_t ws_size,
                              hipStream_t stream) {
    const float* x     = (const float*)d_in[0];
    const float* w_qkv = (const float*)d_in[1];
    const float* b_qkv = (const float*)d_in[2];
    const float* w_out = (const float*)d_in[3];
    const float* b_out = (const float*)d_in[4];
    float* out = (float*)d_out;

    char* wsp = (char*)d_ws;
    float* emb4  = (float*)wsp;                                  // 64 KB
    u16*   wqkvt = (u16*)(wsp + 65536);                          // [1152][384]
    u16*   woutt = (u16*)(wsp + 65536 + 884736);                 // [384][384]
    float* bqkvp = (float*)(wsp + 65536 + 884736 + 294912);      // [1152]
    const size_t fixed = 65536 + 884736 + 294912 + 4608;         // 1,249,792 B

    // per-batch chunk bytes: xb + qkv + att, all bf16
    const size_t perb = (size_t)ROWS_PER_B * (DIM + NQKV + DIM) * 2; // 12,042,240
    int nb = 16;
    while (nb > 2 && fixed + (size_t)nb * perb > ws_size) nb >>= 1;

    u16* xb   = (u16*)(wsp + fixed);
    u16* qkvb = xb   + (size_t)nb * ROWS_PER_B * DIM;
    u16* attb = qkvb + (size_t)nb * ROWS_PER_B * NQKV;

    emb4_init_kernel<<<16, 256, 0, stream>>>(emb4);
    cvt_transpose_qkv<<<(384 * 1152 + 255) / 256, 256, 0, stream>>>(w_qkv, wqkvt);
    cvt_transpose_bf16<<<(384 * 384 + 255) / 256, 256, 0, stream>>>(w_out, woutt, 384, 384);
    bias_perm_kernel<<<5, 256, 0, stream>>>(b_qkv, bqkvp);

    for (int b0 = 0; b0 < 16; b0 += nb) {
        const int rows = nb * ROWS_PER_B;
        const float* xa = x + (size_t)b0 * ROWS_PER_B * DIM;

        cvt_f32_bf16<<<(rows * DIM / 4 + 255) / 256, 256, 0, stream>>>(
            xa, xb, rows * DIM / 4);

        mfma_gemm<0><<<dim3(NQKV / 128, rows / 128), 256, 0, stream>>>(
            xb, wqkvt, bqkvp, qkvb, nullptr, NQKV, DIM);

        attn_mfma_kernel<<<nb * 192, 256, 0, stream>>>(qkvb, emb4, attb);

        mfma_gemm<1><<<dim3(DIM / 128, rows / 128), 256, 0, stream>>>(
            attb, woutt, b_out, nullptr, out + (size_t)b0 * ROWS_PER_B * DIM, DIM, DIM);
    }
}

// Round 18
// 162.940 us; speedup vs baseline: 1.2550x; 1.0044x over previous
//
#include <hip/hip_runtime.h>
#include <math.h>

// Problem constants
#define DIM   384
#define NQKV  1152
#define IMG   56
#define ROWS_PER_B (IMG*IMG)           // 3136 pixels per batch image

typedef unsigned short u16;
typedef unsigned int u32;
typedef __attribute__((ext_vector_type(4))) float f32x4;
typedef __attribute__((ext_vector_type(8))) short s16x8;

__device__ __forceinline__ u16 f2b(float f) {           // fp32 -> bf16 RNE
    unsigned u = __float_as_uint(f);
    return (u16)((u + 0x7fffu + ((u >> 16) & 1u)) >> 16);
}

// async global->LDS, 16B/lane, dest = wave-uniform base + lane*16
__device__ __forceinline__ void gl2lds16(const void* g, void* l) {
    __builtin_amdgcn_global_load_lds(
        (const __attribute__((address_space(1))) void*)g,
        (__attribute__((address_space(3))) void*)l, 16, 0, 0);
}

// ---------------------------------------------------------------------------
// Kernel 1: masked relative-embedding table, 4 variants [4][64][64].
// Sinusoid math bit-faithful to numpy arange fill (verified R3). DO NOT TOUCH.
// ---------------------------------------------------------------------------
__global__ __launch_bounds__(256) void emb4_init_kernel(float* __restrict__ emb4) {
    int idx = blockIdx.x * 256 + threadIdx.x;
    if (idx >= 64 * 64) return;
    int q = idx >> 6, k = idx & 63;

    bool pad = (q >= 49) || (k >= 49);
    float base = 0.f;
    if (!pad) {
        const double step  = 1.0 / 7.0;
        const double delta = __dsub_rn(__dadd_rn(1.0, step), 1.0);
        double xk = __dadd_rn(1.0, __dmul_rn((double)k, delta));
        double xq = __dadd_rn(1.0, __dmul_rn((double)q, delta));
        int xi = (int)__dsub_rn(xk, xq);
        int yi = (k % 7) - (q % 7);
        int r = xi % 13; if (r < 0) r += 13;
        int c = yi % 13; if (c < 0) c += 13;
        const float scl = (float)(-0.7084877209212449);  // -log(10000)/13
        if ((c & 1) == 0) base = sinf((float)r * expf((float)c * scl));
        else              base = cosf((float)r * expf((float)(c - 1) * scl));
    }
    bool rmask = !pad && ((q >= 28) != (k >= 28));
    bool cmask = !pad && ((q % 7 >= 4) != (k % 7 >= 4));
    #pragma unroll
    for (int v = 0; v < 4; ++v) {
        float val = base;
        if (pad || ((v & 1) && rmask) || ((v & 2) && cmask)) val = -INFINITY;
        emb4[v * 4096 + idx] = val;
    }
}

// ---------------------------------------------------------------------------
// Conversion kernels
// ---------------------------------------------------------------------------
__global__ __launch_bounds__(256) void cvt_f32_bf16(
    const float* __restrict__ in, u16* __restrict__ out, int n4) {
    int i = blockIdx.x * 256 + threadIdx.x;
    if (i >= n4) return;
    float4 v = ((const float4*)in)[i];
    ushort4 o;
    o.x = f2b(v.x); o.y = f2b(v.y); o.z = f2b(v.z); o.w = f2b(v.w);
    ((ushort4*)out)[i] = o;
}

__global__ __launch_bounds__(256) void cvt_transpose_bf16(
    const float* __restrict__ w, u16* __restrict__ wt, int R, int C) {
    int i = blockIdx.x * 256 + threadIdx.x;
    if (i >= R * C) return;
    int r = i / C, c = i % C;
    wt[(size_t)c * R + r] = f2b(w[i]);
}

// QKV transpose with de-interleaving row permutation: GEMM col n' = comp*384+ch
__global__ __launch_bounds__(256) void cvt_transpose_qkv(
    const float* __restrict__ w, u16* __restrict__ wt) {
    int i = blockIdx.x * 256 + threadIdx.x;
    if (i >= 384 * 1152) return;
    int k = i / 1152, col = i % 1152;
    int ch = col / 3, comp = col % 3;
    int np = comp * 384 + ch;
    wt[(size_t)np * 384 + k] = f2b(w[i]);
}

__global__ __launch_bounds__(256) void bias_perm_kernel(
    const float* __restrict__ b, float* __restrict__ bp) {
    int n = blockIdx.x * 256 + threadIdx.x;
    if (n >= 1152) return;
    int comp = n / 384, ch = n % 384;
    bp[n] = b[ch * 3 + comp];
}

// ---------------------------------------------------------------------------
// MFMA bf16 GEMM: C[M][N] = A[M][K] @ Bt[N][K]^T + bias.
// 128x128 tile, BK=64, NEW: 8 waves (512 threads), each wave a 64x32 sub-tile
// (wr=wid>>2 row-half, wc=wid&3 col-quarter; acc[4][2] = 32 AGPR/wave).
// Rationale: R17's 4-wave was double-capped at 12 waves/CU (regs 148 -> 3/SIMD
// AND LDS 48KB -> 3 blocks). 8-wave blocks keep LDS/block at 48KB but halve
// per-wave registers (~85 total) -> __launch_bounds__(512,6): 3 blocks x 8
// waves = 24 waves/CU, 2x the latency hiding. LDS frag-reads/MFMA rise
// 0.5 -> 0.75 (bounded, LDS stays below saturation).
// Asymmetric buffering (R17-verified): A dbuf (2x16KB), B single (16KB).
// Per-wave vmcnt ledger: prologue A(0):2+B(0):2; top: STAGE_A(t+1) ->
// vmcnt(2) [A(t),B(t) landed, A(t+1) in flight] -> barrier -> MFMA ->
// lgkm(0)+barrier -> STAGE_B(t+1). Last iter vmcnt(0), drains elided.
// Rule-21 both-sides swizzle (R8-verified 0 conflicts): phys slot8 =
// logical ^ (row&7); inverse folded into gload source slot.
// Grid: bijective XCD remap (m204, R8-verified).
// MODE 0: bf16 out (QKV). MODE 1: fp32 out (final projection).
// ---------------------------------------------------------------------------
template <int MODE>
__global__ __launch_bounds__(512, 6) void mfma_gemm(
    const u16* __restrict__ A, const u16* __restrict__ Bt,
    const float* __restrict__ bias,
    u16* __restrict__ outb, float* __restrict__ outf,
    int N, int K)
{
    __shared__ __align__(16) u16 As[2][8192];   // [128][64] swizzled, dbuf
    __shared__ __align__(16) u16 Bs[8192];      // [128][64] swizzled, single

    const int tid  = threadIdx.x;
    const int lane = tid & 63;
    const int wid  = tid >> 6;                   // 0..7
    const int wr   = wid >> 2, wc = wid & 3;     // 64-row half, 32-col quarter
    const int l15  = lane & 15, l4 = lane >> 4;

    // bijective XCD remap (m204): contiguous chunk of blocks per XCD
    const int gx  = gridDim.x;
    const int nwg = gx * gridDim.y;
    int wg  = blockIdx.y * gx + blockIdx.x;
    int q8  = nwg >> 3, r8 = nwg & 7;
    int xcd = wg & 7, idx = wg >> 3;
    int nid = (xcd < r8 ? xcd * (q8 + 1) : r8 * (q8 + 1) + (xcd - r8) * q8) + idx;
    const int bm = nid / gx, bn = nid % gx;

    // staging: wave wid covers rows wid*16 .. +15 in 2 issues of 8 rows.
    // phys slot = lane&7; source logical slot = (lane&7)^(lane>>3) (row&7 ==
    // lane>>3 since issue rows step by 8).
    const int srow  = lane >> 3;                 // 0..7 within an issue
    const int sslot = (lane & 7) ^ srow;         // pre-swizzled source slot
    const u16* pA[2];
    const u16* pB[2];
    #pragma unroll
    for (int i = 0; i < 2; ++i) {
        pA[i] = A  + (size_t)(bm * 128 + wid * 16 + i * 8 + srow) * K + sslot * 8;
        pB[i] = Bt + (size_t)(bn * 128 + wid * 16 + i * 8 + srow) * K + sslot * 8;
    }

    f32x4 acc[4][2] = {};
    const int NT = K >> 6;                        // BK = 64

    #define STAGE_A(t, b)                                                     \
        do {                                                                  \
            const int _kt = (t) << 6;                                         \
            _Pragma("unroll")                                                 \
            for (int _i = 0; _i < 2; ++_i)                                    \
                gl2lds16(pA[_i] + _kt, &As[b][(wid * 16 + _i * 8) * 64]);     \
        } while (0)
    #define STAGE_B(t)                                                        \
        do {                                                                  \
            const int _kt = (t) << 6;                                         \
            _Pragma("unroll")                                                 \
            for (int _i = 0; _i < 2; ++_i)                                    \
                gl2lds16(pB[_i] + _kt, &Bs[(wid * 16 + _i * 8) * 64]);        \
        } while (0)

    STAGE_A(0, 0);
    STAGE_B(0);

    for (int t = 0; t < NT; ++t) {
        const int buf = t & 1;
        if (t + 1 < NT) {
            STAGE_A(t + 1, buf ^ 1);
            // in-order: A(t) -> B(t) -> A(t+1); leave A(t+1)'s 2 in flight
            asm volatile("s_waitcnt vmcnt(2)" ::: "memory");
        } else {
            asm volatile("s_waitcnt vmcnt(0)" ::: "memory");
        }
        __builtin_amdgcn_s_barrier();          // tile t visible to all waves
        __builtin_amdgcn_sched_barrier(0);

        #pragma unroll
        for (int kk = 0; kk < 2; ++kk) {
            s16x8 af[4], bf[2];
            #pragma unroll
            for (int m = 0; m < 4; ++m) {
                int rm = wr * 64 + m * 16 + l15;
                int sl = (kk * 4 + l4) ^ (rm & 7);
                af[m] = *(const s16x8*)&As[buf][rm * 64 + sl * 8];
            }
            #pragma unroll
            for (int n = 0; n < 2; ++n) {
                int rn = wc * 32 + n * 16 + l15;
                int sl = (kk * 4 + l4) ^ (rn & 7);
                bf[n] = *(const s16x8*)&Bs[rn * 64 + sl * 8];
            }
            #pragma unroll
            for (int m = 0; m < 4; ++m)
                #pragma unroll
                for (int n = 0; n < 2; ++n)
                    acc[m][n] = __builtin_amdgcn_mfma_f32_16x16x32_bf16(
                        af[m], bf[n], acc[m][n], 0, 0, 0);
        }

        if (t + 1 < NT) {
            // all waves' reads of Bs (and As[buf]) retired before new B lands
            asm volatile("s_waitcnt lgkmcnt(0)" ::: "memory");
            __builtin_amdgcn_sched_barrier(0);
            __builtin_amdgcn_s_barrier();
            STAGE_B(t + 1);                     // safe overwrite of Bs
        }
    }
    #undef STAGE_A
    #undef STAGE_B

    const int grow0 = bm * 128 + wr * 64;
    const int gcol0 = bn * 128 + wc * 32;
    #pragma unroll
    for (int m = 0; m < 4; ++m) {
        #pragma unroll
        for (int n = 0; n < 2; ++n) {
            int col = gcol0 + n * 16 + l15;
            float bz = bias[col];
            #pragma unroll
            for (int r = 0; r < 4; ++r) {
                int row = grow0 + m * 16 + l4 * 4 + r;
                float v = acc[m][n][r] + bz;
                if constexpr (MODE == 0)
                    outb[(size_t)row * N + col] = f2b(v);
                else
                    outf[(size_t)row * N + col] = v;
            }
        }
    }
}

// ---------------------------------------------------------------------------
// Kernel 3: MFMA windowed attention, stageless (verified R7) + T5 setprio +
// T14 issue-early V loads (R16). Unchanged.
// ---------------------------------------------------------------------------
__global__ __launch_bounds__(256) void attn_mfma_kernel(
    const u16* __restrict__ qkv, const float* __restrict__ emb4,
    u16* __restrict__ att)
{
    __shared__ __align__(16) u16 P4[4][64 * 72];   // 36864 B
    __shared__ int rowIn[64];
    __shared__ int rowOut[64];

    const int tid  = threadIdx.x;
    const int lane = tid & 63;
    const int wid  = tid >> 6;
    const int l15  = lane & 15, l4 = lane >> 4;

    const int blk = blockIdx.x;
    const int hg  = blk % 3;
    const int win = (blk / 3) & 63;
    const int b   = blk / 192;
    const int bw  = win & 7, bh = win >> 3;
    const int head = hg * 4 + wid;

    if (tid < 64) {                                 // roll(-4,-4) gather LUT
        int pix = tid;
        int gr = (bh * 7 + pix / 7 + 4) % IMG;
        int gc = (bw * 7 + pix % 7 + 4) % IMG;
        rowIn[pix] = (b * IMG + gr) * IMG + gc;
    } else if (tid < 128) {                         // roll(+3,+3) scatter LUT
        int q = tid - 64;
        int fr = (bh * 7 + q / 7 + 3) % IMG;
        int fc = (bw * 7 + q % 7 + 3) % IMG;
        rowOut[q] = (b * IMG + fr) * IMG + fc;
    }
    __syncthreads();

    // ---- issue ALL global loads up front (Q, K fragments + V fragments) ----
    s16x8 qf[4], kf[4];
    #pragma unroll
    for (int n = 0; n < 4; ++n) {
        int pix = n * 16 + l15;
        size_t base = (size_t)rowIn[pix] * NQKV + head * 32 + l4 * 8;
        qf[n] = *(const s16x8*)(qkv + base);          // Q
        kf[n] = *(const s16x8*)(qkv + base + 384);    // K
    }
    s16x8 vf[2][2];                                   // [kh][ne], +16 VGPR
    #pragma unroll
    for (int kh = 0; kh < 2; ++kh)
        #pragma unroll
        for (int ne = 0; ne < 2; ++ne)
            #pragma unroll
            for (int j = 0; j < 8; ++j) {
                int pix = kh * 32 + l4 * 8 + j;
                vf[kh][ne][j] = (short)qkv[(size_t)rowIn[pix] * NQKV + 768
                                           + head * 32 + ne * 16 + l15];
            }

    f32x4 sc[4][4] = {};
    __builtin_amdgcn_s_setprio(1);
    #pragma unroll
    for (int m = 0; m < 4; ++m)
        #pragma unroll
        for (int n = 0; n < 4; ++n)
            sc[m][n] = __builtin_amdgcn_mfma_f32_16x16x32_bf16(
                kf[m], qf[n], sc[m][n], 0, 0, 0);
    __builtin_amdgcn_s_setprio(0);

    const float scale = 0.17677669529663687f;        // 1/sqrt(32)
    const float* ev = emb4 + ((bh == 7 ? 1 : 0) + (bw == 7 ? 2 : 0)) * 4096;
    u16* P = P4[wid];
    u32* P32 = (u32*)P;

    #pragma unroll
    for (int n = 0; n < 4; ++n) {
        const int q = n * 16 + l15;
        float vals[4][4];
        float mx = -INFINITY;
        #pragma unroll
        for (int m = 0; m < 4; ++m) {
            float4 e4 = *(const float4*)(ev + q * 64 + m * 16 + l4 * 4);
            #pragma unroll
            for (int r = 0; r < 4; ++r) {
                float v = sc[m][n][r] * scale + ((const float*)&e4)[r];
                vals[m][r] = v;
                mx = fmaxf(mx, v);
            }
        }
        mx = fmaxf(mx, __shfl_xor(mx, 16));
        mx = fmaxf(mx, __shfl_xor(mx, 32));
        float sum = 0.f;
        #pragma unroll
        for (int m = 0; m < 4; ++m)
            #pragma unroll
            for (int r = 0; r < 4; ++r) {
                float p = __expf(vals[m][r] - mx);
                vals[m][r] = p;
                sum += p;
            }
        sum += __shfl_xor(sum, 16);
        sum += __shfl_xor(sum, 32);
        float inv = 1.f / sum;
        #pragma unroll
        for (int m = 0; m < 4; ++m) {
            u32 w0 = (u32)f2b(vals[m][0] * inv) | ((u32)f2b(vals[m][1] * inv) << 16);
            u32 w1 = (u32)f2b(vals[m][2] * inv) | ((u32)f2b(vals[m][3] * inv) << 16);
            int bidx = q * 36 + m * 8 + l4 * 2;
            P32[bidx]     = w0;
            P32[bidx + 1] = w1;
        }
    }
    // per-wave private LDS RAW: compiler inserts lgkmcnt waits; no barrier.

    f32x4 o[4][2] = {};
    #pragma unroll
    for (int kh = 0; kh < 2; ++kh) {
        s16x8 pf[4];
        #pragma unroll
        for (int mq = 0; mq < 4; ++mq)
            pf[mq] = *(const s16x8*)&P[(mq * 16 + l15) * 72 + kh * 32 + l4 * 8];
        __builtin_amdgcn_s_setprio(1);
        #pragma unroll
        for (int mq = 0; mq < 4; ++mq)
            #pragma unroll
            for (int ne = 0; ne < 2; ++ne)
                o[mq][ne] = __builtin_amdgcn_mfma_f32_16x16x32_bf16(
                    pf[mq], vf[kh][ne], o[mq][ne], 0, 0, 0);
        __builtin_amdgcn_s_setprio(0);
    }

    #pragma unroll
    for (int mq = 0; mq < 4; ++mq) {
        #pragma unroll
        for (int r = 0; r < 4; ++r) {
            int q = mq * 16 + l4 * 4 + r;
            if (q < 49) {
                size_t rowb = (size_t)rowOut[q] * DIM + head * 32;
                #pragma unroll
                for (int ne = 0; ne < 2; ++ne)
                    att[rowb + ne * 16 + l15] = f2b(o[mq][ne][r]);
            }
        }
    }
}

// ---------------------------------------------------------------------------
extern "C" void kernel_launch(void* const* d_in, const int* in_sizes, int n_in,
                              void* d_out, int out_size, void* d_ws, size_t ws_size,
                              hipStream_t stream) {
    const float* x     = (const float*)d_in[0];
    const float* w_qkv = (const float*)d_in[1];
    const float* b_qkv = (const float*)d_in[2];
    const float* w_out = (const float*)d_in[3];
    const float* b_out = (const float*)d_in[4];
    float* out = (float*)d_out;

    char* wsp = (char*)d_ws;
    float* emb4  = (float*)wsp;                                  // 64 KB
    u16*   wqkvt = (u16*)(wsp + 65536);                          // [1152][384]
    u16*   woutt = (u16*)(wsp + 65536 + 884736);                 // [384][384]
    float* bqkvp = (float*)(wsp + 65536 + 884736 + 294912);      // [1152]
    const size_t fixed = 65536 + 884736 + 294912 + 4608;         // 1,249,792 B

    // per-batch chunk bytes: xb + qkv + att, all bf16
    const size_t perb = (size_t)ROWS_PER_B * (DIM + NQKV + DIM) * 2; // 12,042,240
    int nb = 16;
    while (nb > 2 && fixed + (size_t)nb * perb > ws_size) nb >>= 1;

    u16* xb   = (u16*)(wsp + fixed);
    u16* qkvb = xb   + (size_t)nb * ROWS_PER_B * DIM;
    u16* attb = qkvb + (size_t)nb * ROWS_PER_B * NQKV;

    emb4_init_kernel<<<16, 256, 0, stream>>>(emb4);
    cvt_transpose_qkv<<<(384 * 1152 + 255) / 256, 256, 0, stream>>>(w_qkv, wqkvt);
    cvt_transpose_bf16<<<(384 * 384 + 255) / 256, 256, 0, stream>>>(w_out, woutt, 384, 384);
    bias_perm_kernel<<<5, 256, 0, stream>>>(b_qkv, bqkvp);

    for (int b0 = 0; b0 < 16; b0 += nb) {
        const int rows = nb * ROWS_PER_B;
        const float* xa = x + (size_t)b0 * ROWS_PER_B * DIM;

        cvt_f32_bf16<<<(rows * DIM / 4 + 255) / 256, 256, 0, stream>>>(
            xa, xb, rows * DIM / 4);

        mfma_gemm<0><<<dim3(NQKV / 128, rows / 128), 512, 0, stream>>>(
            xb, wqkvt, bqkvp, qkvb, nullptr, NQKV, DIM);

        attn_mfma_kernel<<<nb * 192, 256, 0, stream>>>(qkvb, emb4, attb);

        mfma_gemm<1><<<dim3(DIM / 128, rows / 128), 512, 0, stream>>>(
            attb, woutt, b_out, nullptr, out + (size_t)b0 * ROWS_PER_B * DIM, DIM, DIM);
    }
}